// Round 1
// baseline (866.653 us; speedup 1.0000x reference)
//
#include <hip/hip_runtime.h>
#include <cstdint>
#include <cstddef>

// ---------------- problem constants ----------------
#define NN 50000
#define EE 1600000
#define IN_DIM 256
#define HC 128      // HEADS*C
#define CD 32       // C
#define BN_RS 0.9999950000374997f  // 1/sqrt(1+1e-5)

#define CAP1 128
#define CAP2 128

// ---------------- small helpers ----------------
__device__ __forceinline__ float lrelu(float a) { return a > 0.f ? a : 0.2f * a; }
__device__ __forceinline__ float elu(float a) { return a > 0.f ? a : (__expf(a) - 1.f); }

// ---------------- edge_attr mean: sum reduce ----------------
__global__ void ea_sum_kernel(const float* __restrict__ ea, float* __restrict__ out) {
    int idx = blockIdx.x * blockDim.x + threadIdx.x;
    int stride = gridDim.x * blockDim.x;
    float s = 0.f;
    for (int i = idx; i < EE; i += stride) s += ea[i];
    #pragma unroll
    for (int off = 32; off > 0; off >>= 1) s += __shfl_xor(s, off);
    if ((threadIdx.x & 63) == 0) atomicAdd(out, s);
}

// ---------------- CSR build ----------------
__global__ void count_kernel(const int* __restrict__ ei, int* __restrict__ counts) {
    int i = blockIdx.x * 256 + threadIdx.x;
    if (i < EE) atomicAdd(&counts[ei[EE + i]], 1);
}

__global__ void scan_kernel(const int* __restrict__ counts, int* __restrict__ indptr,
                            int* __restrict__ cursor, int n) {
    __shared__ int buf[1024];
    __shared__ int s_carry;
    int tid = threadIdx.x;
    if (tid == 0) s_carry = 0;
    __syncthreads();
    for (int base = 0; base < n; base += 1024) {
        int i = base + tid;
        int v = (i < n) ? counts[i] : 0;
        buf[tid] = v;
        __syncthreads();
        for (int off = 1; off < 1024; off <<= 1) {
            int t = (tid >= off) ? buf[tid - off] : 0;
            __syncthreads();
            buf[tid] += t;
            __syncthreads();
        }
        int incl = buf[tid];
        int tot = buf[1023];
        int c = s_carry;
        if (i < n) { indptr[i] = c + incl - v; cursor[i] = c + incl - v; }
        __syncthreads();
        if (tid == 0) s_carry = c + tot;
        __syncthreads();
    }
    if (tid == 0) indptr[n] = s_carry;
}

__global__ void scatter_kernel(const int* __restrict__ ei, int* __restrict__ cursor,
                               int* __restrict__ bucket) {
    int i = blockIdx.x * 256 + threadIdx.x;
    if (i < EE) {
        int d = ei[EE + i];
        int pos = atomicAdd(&cursor[d], 1);
        bucket[pos] = i;
    }
}

// ---------------- per-head attention constants + ea mean ----------------
__global__ void prep_kernel(const float* __restrict__ We1, const float* __restrict__ ae1,
                            const float* __restrict__ We2, const float* __restrict__ ae2,
                            float* __restrict__ consts) {
    int lane = threadIdx.x;
    if (lane < 4) {
        float s = 0.f;
        for (int c = 0; c < 32; c++) s += We1[lane * 32 + c] * ae1[lane * 32 + c];
        consts[2 + lane] = s;
    } else if (lane == 4) {
        float s = 0.f;
        for (int c = 0; c < 32; c++) s += We2[c] * ae2[c];
        consts[6] = s;
    } else if (lane == 5) {
        consts[1] = consts[0] / (float)EE;
    }
}

// ---------------- fp32 tiled GEMM: C[M,TN] = A[M,K] @ B[K,TN] ----------------
template <int TM, int TN, int TK, int RM, int RN>
__global__ __launch_bounds__(256) void gemm_kernel(const float* __restrict__ A,
                                                   const float* __restrict__ B,
                                                   float* __restrict__ C, int M, int K) {
    static_assert(TM * TN == 256 * RM * RN, "thread coverage");
    __shared__ float As[TK][TM + 4];
    __shared__ float Bs[TK][TN];
    int tid = threadIdx.x;
    int tx = tid % (TN / RN);
    int ty = tid / (TN / RN);
    int blockRow = blockIdx.x * TM;
    float acc[RM][RN];
    #pragma unroll
    for (int i = 0; i < RM; i++)
        #pragma unroll
        for (int j = 0; j < RN; j++) acc[i][j] = 0.f;

    for (int k0 = 0; k0 < K; k0 += TK) {
        #pragma unroll
        for (int l = 0; l < TM * TK; l += 256 * 4) {
            int ll = l + tid * 4;
            if (ll < TM * TK) {
                int r = ll / TK, kk = ll % TK;
                float4 v = make_float4(0.f, 0.f, 0.f, 0.f);
                int gr = blockRow + r;
                if (gr < M) v = *(const float4*)(A + (size_t)gr * K + k0 + kk);
                As[kk + 0][r] = v.x;
                As[kk + 1][r] = v.y;
                As[kk + 2][r] = v.z;
                As[kk + 3][r] = v.w;
            }
        }
        #pragma unroll
        for (int l = 0; l < TK * TN; l += 256 * 4) {
            int ll = l + tid * 4;
            if (ll < TK * TN) {
                int kk = ll / TN, c = ll % TN;
                *(float4*)&Bs[kk][c] = *(const float4*)(B + (size_t)(k0 + kk) * TN + c);
            }
        }
        __syncthreads();
        #pragma unroll
        for (int k = 0; k < TK; k++) {
            float af[RM], bf[RN];
            #pragma unroll
            for (int i = 0; i < RM; i++) af[i] = As[k][ty * RM + i];
            #pragma unroll
            for (int j = 0; j < RN; j++) bf[j] = Bs[k][tx * RN + j];
            #pragma unroll
            for (int i = 0; i < RM; i++)
                #pragma unroll
                for (int j = 0; j < RN; j++) acc[i][j] += af[i] * bf[j];
        }
        __syncthreads();
    }
    #pragma unroll
    for (int i = 0; i < RM; i++) {
        int gr = blockRow + ty * RM + i;
        if (gr < M) {
            #pragma unroll
            for (int j = 0; j < RN; j++) C[(size_t)gr * TN + tx * RN + j] = acc[i][j];
        }
    }
}

// ---------------- attention logits per node ----------------
__global__ void al1_kernel(const float* __restrict__ xs1, const float* __restrict__ as1,
                           const float* __restrict__ ad1, float* __restrict__ als,
                           float* __restrict__ ald) {
    int t = blockIdx.x * 256 + threadIdx.x;
    if (t >= NN * 4) return;
    int h = t & 3;
    const float* xp = xs1 + (size_t)t * 32;  // node*128 + h*32 == t*32
    const float* ap = as1 + h * 32;
    const float* dp = ad1 + h * 32;
    float s = 0.f, d = 0.f;
    #pragma unroll
    for (int c = 0; c < 32; c += 4) {
        float4 xv = *(const float4*)(xp + c);
        float4 av = *(const float4*)(ap + c);
        float4 dv = *(const float4*)(dp + c);
        s += xv.x * av.x + xv.y * av.y + xv.z * av.z + xv.w * av.w;
        d += xv.x * dv.x + xv.y * dv.y + xv.z * dv.z + xv.w * dv.w;
    }
    als[t] = s;
    ald[t] = d;
}

__global__ void al2_kernel(const float* __restrict__ xs2, const float* __restrict__ as2,
                           const float* __restrict__ ad2, float* __restrict__ als,
                           float* __restrict__ ald) {
    int t = blockIdx.x * 256 + threadIdx.x;
    if (t >= NN) return;
    const float* xp = xs2 + (size_t)t * 32;
    float s = 0.f, d = 0.f;
    #pragma unroll
    for (int c = 0; c < 32; c += 4) {
        float4 xv = *(const float4*)(xp + c);
        float4 av = *(const float4*)(as2 + c);
        float4 dv = *(const float4*)(ad2 + c);
        s += xv.x * av.x + xv.y * av.y + xv.z * av.z + xv.w * av.w;
        d += xv.x * dv.x + xv.y * dv.y + xv.z * dv.z + xv.w * dv.w;
    }
    als[t] = s;
    ald[t] = d;
}

// ---------------- conv1 aggregation: one wave per dst node (H=4, F=128) ----------------
__global__ __launch_bounds__(256) void gat1_agg(
    const float* __restrict__ xs1, const float* __restrict__ als, const float* __restrict__ ald,
    const int* __restrict__ ei, const float* __restrict__ ea, const int* __restrict__ indptr,
    const int* __restrict__ bucket, const float* __restrict__ consts,
    const float* __restrict__ b1, const float* __restrict__ g1, const float* __restrict__ be1,
    float* __restrict__ h1out) {
    __shared__ float exbuf[4][CAP1 * 4];
    __shared__ int srcbuf[4][CAP1];
    int wv = threadIdx.x >> 6;
    int lane = threadIdx.x & 63;
    int n = blockIdx.x * 4 + wv;
    if (n >= NN) return;
    int start = indptr[n];
    int deg = indptr[n + 1] - start;
    float ea_mean = consts[1];
    float ce[4] = {consts[2], consts[3], consts[4], consts[5]};
    float4 a4d = *(const float4*)(ald + (size_t)n * 4);
    float aldh[4] = {a4d.x, a4d.y, a4d.z, a4d.w};
    float4 a4s = *(const float4*)(als + (size_t)n * 4);
    float alsn[4] = {a4s.x, a4s.y, a4s.z, a4s.w};
    float asl[4], mx[4];
    #pragma unroll
    for (int h = 0; h < 4; h++) {
        float a = lrelu(alsn[h] + aldh[h] + ea_mean * ce[h]);
        asl[h] = a;
        mx[h] = a;
    }
    const int* bkt = bucket + start;
    // phase 1: alpha + max
    for (int i = lane; i < deg; i += 64) {
        int e = bkt[i];
        int s = ei[e];
        float eav = ea[e];
        float4 v4 = *(const float4*)(als + (size_t)s * 4);
        float alv[4] = {v4.x, v4.y, v4.z, v4.w};
        bool st = (i < CAP1);
        if (st) srcbuf[wv][i] = s;
        #pragma unroll
        for (int h = 0; h < 4; h++) {
            float a = lrelu(alv[h] + aldh[h] + eav * ce[h]);
            if (st) exbuf[wv][i * 4 + h] = a;
            mx[h] = fmaxf(mx[h], a);
        }
    }
    #pragma unroll
    for (int h = 0; h < 4; h++)
        for (int off = 32; off > 0; off >>= 1) mx[h] = fmaxf(mx[h], __shfl_xor(mx[h], off));
    // phase 2: sum of exp
    float sm[4] = {0.f, 0.f, 0.f, 0.f};
    for (int i = lane; i < deg; i += 64) {
        if (i < CAP1) {
            #pragma unroll
            for (int h = 0; h < 4; h++) {
                float exv = __expf(exbuf[wv][i * 4 + h] - mx[h]);
                exbuf[wv][i * 4 + h] = exv;
                sm[h] += exv;
            }
        } else {
            int e = bkt[i];
            int s = ei[e];
            float eav = ea[e];
            float4 v4 = *(const float4*)(als + (size_t)s * 4);
            float alv[4] = {v4.x, v4.y, v4.z, v4.w};
            #pragma unroll
            for (int h = 0; h < 4; h++) {
                float a = lrelu(alv[h] + aldh[h] + eav * ce[h]);
                sm[h] += __expf(a - mx[h]);
            }
        }
    }
    #pragma unroll
    for (int h = 0; h < 4; h++)
        for (int off = 32; off > 0; off >>= 1) sm[h] += __shfl_xor(sm[h], off);
    float inv[4];
    #pragma unroll
    for (int h = 0; h < 4; h++) inv[h] = 1.0f / (sm[h] + __expf(asl[h] - mx[h]) + 1e-16f);
    // phase 3: weighted gather; lane holds features c, c+1
    int c = lane * 2;
    int h = lane >> 4;
    float winv = inv[h];
    float wsl = __expf(asl[h] - mx[h]) * winv;
    float2 vself = *(const float2*)(xs1 + (size_t)n * HC + c);
    float accx = vself.x * wsl, accy = vself.y * wsl;
    int m = deg < CAP1 ? deg : CAP1;
    int i = 0;
    for (; i + 4 <= m; i += 4) {
        float w0 = exbuf[wv][(i + 0) * 4 + h] * winv;
        float w1 = exbuf[wv][(i + 1) * 4 + h] * winv;
        float w2 = exbuf[wv][(i + 2) * 4 + h] * winv;
        float w3 = exbuf[wv][(i + 3) * 4 + h] * winv;
        int s0 = srcbuf[wv][i + 0], s1 = srcbuf[wv][i + 1];
        int s2 = srcbuf[wv][i + 2], s3 = srcbuf[wv][i + 3];
        float2 v0 = *(const float2*)(xs1 + (size_t)s0 * HC + c);
        float2 v1 = *(const float2*)(xs1 + (size_t)s1 * HC + c);
        float2 v2 = *(const float2*)(xs1 + (size_t)s2 * HC + c);
        float2 v3 = *(const float2*)(xs1 + (size_t)s3 * HC + c);
        accx += v0.x * w0; accy += v0.y * w0;
        accx += v1.x * w1; accy += v1.y * w1;
        accx += v2.x * w2; accy += v2.y * w2;
        accx += v3.x * w3; accy += v3.y * w3;
    }
    for (; i < m; i++) {
        float w0 = exbuf[wv][i * 4 + h] * winv;
        int s0 = srcbuf[wv][i];
        float2 v0 = *(const float2*)(xs1 + (size_t)s0 * HC + c);
        accx += v0.x * w0; accy += v0.y * w0;
    }
    for (; i < deg; i++) {  // LDS-spill fallback (deg > CAP1): recompute
        int e = bkt[i];
        int s = ei[e];
        float eav = ea[e];
        float a = lrelu(als[(size_t)s * 4 + h] + aldh[h] + eav * ce[h]);
        float w0 = __expf(a - mx[h]) * winv;
        float2 v0 = *(const float2*)(xs1 + (size_t)s * HC + c);
        accx += v0.x * w0; accy += v0.y * w0;
    }
    // epilogue: +bias, bn(eval), elu
    float o0 = accx + b1[c];
    float o1 = accy + b1[c + 1];
    o0 = o0 * (g1[c] * BN_RS) + be1[c];
    o1 = o1 * (g1[c + 1] * BN_RS) + be1[c + 1];
    o0 = elu(o0);
    o1 = elu(o1);
    *(float2*)(h1out + (size_t)n * HC + c) = make_float2(o0, o1);
}

// ---------------- conv2 aggregation: one wave per dst node (H=1, F=32) ----------------
__global__ __launch_bounds__(256) void gat2_agg(
    const float* __restrict__ xs2, const float* __restrict__ als, const float* __restrict__ ald,
    const int* __restrict__ ei, const float* __restrict__ ea, const int* __restrict__ indptr,
    const int* __restrict__ bucket, const float* __restrict__ consts,
    const float* __restrict__ b2, const float* __restrict__ g2, const float* __restrict__ be2,
    float* __restrict__ hout) {
    __shared__ float exbuf[4][CAP2];
    __shared__ int srcbuf[4][CAP2];
    int wv = threadIdx.x >> 6;
    int lane = threadIdx.x & 63;
    int n = blockIdx.x * 4 + wv;
    if (n >= NN) return;
    int start = indptr[n];
    int deg = indptr[n + 1] - start;
    float ea_mean = consts[1];
    float ce = consts[6];
    float aldn = ald[n];
    float a0 = lrelu(als[n] + aldn + ea_mean * ce);
    float mx = a0;
    const int* bkt = bucket + start;
    for (int i = lane; i < deg; i += 64) {
        int e = bkt[i];
        int s = ei[e];
        float eav = ea[e];
        float a = lrelu(als[s] + aldn + eav * ce);
        if (i < CAP2) { srcbuf[wv][i] = s; exbuf[wv][i] = a; }
        mx = fmaxf(mx, a);
    }
    for (int off = 32; off > 0; off >>= 1) mx = fmaxf(mx, __shfl_xor(mx, off));
    float sm = 0.f;
    for (int i = lane; i < deg; i += 64) {
        if (i < CAP2) {
            float exv = __expf(exbuf[wv][i] - mx);
            exbuf[wv][i] = exv;
            sm += exv;
        } else {
            int e = bkt[i];
            int s = ei[e];
            float eav = ea[e];
            float a = lrelu(als[s] + aldn + eav * ce);
            sm += __expf(a - mx);
        }
    }
    for (int off = 32; off > 0; off >>= 1) sm += __shfl_xor(sm, off);
    float invd = 1.0f / (sm + __expf(a0 - mx) + 1e-16f);
    // phase 3: two edges in parallel via lane halves; each half covers features 0..31
    int c = lane & 31;
    int half = lane >> 5;
    float acc = 0.f;
    if (half == 0) acc = xs2[(size_t)n * CD + c] * (__expf(a0 - mx) * invd);
    int m = deg < CAP2 ? deg : CAP2;
    for (int i = half; i < m; i += 2) {
        float w0 = exbuf[wv][i] * invd;
        int s0 = srcbuf[wv][i];
        acc += xs2[(size_t)s0 * CD + c] * w0;
    }
    for (int i = CAP2 + half; i < deg; i += 2) {  // spill fallback
        int e = bkt[i];
        int s = ei[e];
        float eav = ea[e];
        float a = lrelu(als[s] + aldn + eav * ce);
        float w0 = __expf(a - mx) * invd;
        acc += xs2[(size_t)s * CD + c] * w0;
    }
    acc += __shfl_xor(acc, 32);
    if (half == 0) {
        float o = acc + b2[c];
        o = o * (g2[c] * BN_RS) + be2[c];
        o = elu(o);
        hout[(size_t)n * CD + c] = o;
    }
}

// ---------------- classifier + regressor heads ----------------
__global__ __launch_bounds__(256) void head_kernel(
    const float* __restrict__ h2, const float* __restrict__ Wc1, const float* __restrict__ bc1,
    const float* __restrict__ Wc2, const float* __restrict__ bc2,
    const float* __restrict__ Wr1, const float* __restrict__ br1,
    const float* __restrict__ Wr2, const float* __restrict__ br2,
    float* __restrict__ cls, float* __restrict__ reg) {
    int n = blockIdx.x * 256 + threadIdx.x;
    if (n >= NN) return;
    float hv[32];
    const float4* hp = (const float4*)(h2 + (size_t)n * 32);
    #pragma unroll
    for (int q = 0; q < 8; q++) {
        float4 t = hp[q];
        hv[q * 4] = t.x; hv[q * 4 + 1] = t.y; hv[q * 4 + 2] = t.z; hv[q * 4 + 3] = t.w;
    }
    float c0 = bc2[0], c1 = bc2[1];
    #pragma unroll
    for (int j = 0; j < 16; j++) {
        float s = bc1[j];
        #pragma unroll
        for (int cc = 0; cc < 32; cc++) s += hv[cc] * Wc1[cc * 16 + j];
        s = fmaxf(s, 0.f);
        c0 += s * Wc2[j * 2];
        c1 += s * Wc2[j * 2 + 1];
    }
    *(float2*)(cls + (size_t)n * 2) = make_float2(c0, c1);
    float r = br2[0];
    #pragma unroll
    for (int j = 0; j < 16; j++) {
        float s = br1[j];
        #pragma unroll
        for (int cc = 0; cc < 32; cc++) s += hv[cc] * Wr1[cc * 16 + j];
        s = fmaxf(s, 0.f);
        r += s * Wr2[j];
    }
    reg[n] = r;
}

// ---------------- launch ----------------
extern "C" void kernel_launch(void* const* d_in, const int* in_sizes, int n_in,
                              void* d_out, int out_size, void* d_ws, size_t ws_size,
                              hipStream_t stream) {
    const float* x   = (const float*)d_in[0];
    const int*   ei  = (const int*)d_in[1];
    const float* ea  = (const float*)d_in[2];
    const float* W1  = (const float*)d_in[3];
    const float* as1 = (const float*)d_in[4];
    const float* ad1 = (const float*)d_in[5];
    const float* We1 = (const float*)d_in[6];
    const float* ae1 = (const float*)d_in[7];
    const float* b1  = (const float*)d_in[8];
    const float* g1  = (const float*)d_in[9];
    const float* be1 = (const float*)d_in[10];
    const float* W2  = (const float*)d_in[11];
    const float* as2 = (const float*)d_in[12];
    const float* ad2 = (const float*)d_in[13];
    const float* We2 = (const float*)d_in[14];
    const float* ae2 = (const float*)d_in[15];
    const float* b2  = (const float*)d_in[16];
    const float* g2  = (const float*)d_in[17];
    const float* be2 = (const float*)d_in[18];
    const float* Wc1 = (const float*)d_in[19];
    const float* bc1 = (const float*)d_in[20];
    const float* Wc2 = (const float*)d_in[21];
    const float* bc2 = (const float*)d_in[22];
    const float* Wr1 = (const float*)d_in[23];
    const float* br1 = (const float*)d_in[24];
    const float* Wr2 = (const float*)d_in[25];
    const float* br2 = (const float*)d_in[26];

    char* ws = (char*)d_ws;
    float* xs1    = (float*)(ws + 0);          // N*128 f32 = 25.6 MB
    float* h1     = (float*)(ws + 25600000);   // N*128
    float* xs2    = (float*)(ws + 51200000);   // N*32
    float* als1   = (float*)(ws + 57600000);   // N*4
    float* ald1   = (float*)(ws + 58400000);   // N*4
    float* als2   = (float*)(ws + 59200000);   // N
    float* ald2   = (float*)(ws + 59400000);   // N
    float* consts = (float*)(ws + 59600000);   // [ea_sum, ea_mean, ce1[4], ce2]
    int*   counts = (int*)(ws + 59600256);     // N
    int*   indptr = (int*)(ws + 59800256);     // N+1
    int*   cursor = (int*)(ws + 60000512);     // N
    int*   bucket = (int*)(ws + 60200512);     // E   (total ~66.6 MB)

    float* out_cls = (float*)d_out;            // [N,2]
    float* out_reg = out_cls + 2 * NN;         // [N]
    float* out_h   = out_cls + 3 * NN;         // [N,32]

    hipMemsetAsync(counts, 0, NN * sizeof(int), stream);
    hipMemsetAsync(consts, 0, 8 * sizeof(float), stream);

    // edge mean + CSR build
    ea_sum_kernel<<<256, 256, 0, stream>>>(ea, consts);
    count_kernel<<<(EE + 255) / 256, 256, 0, stream>>>(ei, counts);
    scan_kernel<<<1, 1024, 0, stream>>>(counts, indptr, cursor, NN);
    scatter_kernel<<<(EE + 255) / 256, 256, 0, stream>>>(ei, cursor, bucket);
    prep_kernel<<<1, 64, 0, stream>>>(We1, ae1, We2, ae2, consts);

    // conv1
    gemm_kernel<64, 128, 32, 4, 8><<<(NN + 63) / 64, 256, 0, stream>>>(x, W1, xs1, NN, IN_DIM);
    al1_kernel<<<(NN * 4 + 255) / 256, 256, 0, stream>>>(xs1, as1, ad1, als1, ald1);
    gat1_agg<<<(NN + 3) / 4, 256, 0, stream>>>(xs1, als1, ald1, ei, ea, indptr, bucket,
                                               consts, b1, g1, be1, h1);
    // conv2
    gemm_kernel<128, 32, 32, 8, 2><<<(NN + 127) / 128, 256, 0, stream>>>(h1, W2, xs2, NN, HC);
    al2_kernel<<<(NN + 255) / 256, 256, 0, stream>>>(xs2, as2, ad2, als2, ald2);
    gat2_agg<<<(NN + 3) / 4, 256, 0, stream>>>(xs2, als2, ald2, ei, ea, indptr, bucket,
                                               consts, b2, g2, be2, out_h);
    // heads
    head_kernel<<<(NN + 255) / 256, 256, 0, stream>>>(out_h, Wc1, bc1, Wc2, bc2,
                                                      Wr1, br1, Wr2, br2, out_cls, out_reg);
}

// Round 2
// 760.338 us; speedup vs baseline: 1.1398x; 1.1398x over previous
//
#include <hip/hip_runtime.h>
#include <cstdint>
#include <cstddef>

// ---------------- problem constants ----------------
#define NN 50000
#define EE 1600000
#define IN_DIM 256
#define HC 128      // HEADS*C
#define CD 32       // C
#define BN_RS 0.9999950000374997f  // 1/sqrt(1+1e-5)

#define CAP1 128
#define CAP2 128

// ---------------- small helpers ----------------
__device__ __forceinline__ float lrelu(float a) { return a > 0.f ? a : 0.2f * a; }
__device__ __forceinline__ float elu(float a) { return a > 0.f ? a : (__expf(a) - 1.f); }

// bf16 (stored as ushort bits) <-> f32
__device__ __forceinline__ unsigned short f2bf(float f) {
    unsigned int u = __float_as_uint(f);
    unsigned int r = (u + 0x7FFFu + ((u >> 16) & 1u)) >> 16;
    return (unsigned short)r;
}
__device__ __forceinline__ float2 bf2f2(unsigned int p) {
    float2 r;
    r.x = __uint_as_float(p << 16);
    r.y = __uint_as_float(p & 0xFFFF0000u);
    return r;
}

// ---------------- edge_attr mean: sum reduce ----------------
__global__ void ea_sum_kernel(const float* __restrict__ ea, float* __restrict__ out) {
    int idx = blockIdx.x * blockDim.x + threadIdx.x;
    int stride = gridDim.x * blockDim.x;
    float s = 0.f;
    for (int i = idx; i < EE; i += stride) s += ea[i];
    #pragma unroll
    for (int off = 32; off > 0; off >>= 1) s += __shfl_xor(s, off);
    if ((threadIdx.x & 63) == 0) atomicAdd(out, s);
}

// ---------------- CSR build ----------------
__global__ void count_kernel(const int* __restrict__ ei, int* __restrict__ counts) {
    int i = blockIdx.x * 256 + threadIdx.x;
    if (i < EE) atomicAdd(&counts[ei[EE + i]], 1);
}

// wave-shuffle based single-block scan: 3 barriers per 1024-chunk
__global__ void scan_kernel(const int* __restrict__ counts, int* __restrict__ indptr,
                            int* __restrict__ cursor, int n) {
    __shared__ int wsum[16];
    __shared__ int s_carry;
    int tid = threadIdx.x, lane = tid & 63, wv = tid >> 6;
    if (tid == 0) s_carry = 0;
    __syncthreads();
    for (int base = 0; base < n; base += 1024) {
        int i = base + tid;
        int v = (i < n) ? counts[i] : 0;
        int x = v;
        #pragma unroll
        for (int off = 1; off < 64; off <<= 1) {
            int t = __shfl_up(x, off);
            if (lane >= off) x += t;
        }
        if (lane == 63) wsum[wv] = x;
        __syncthreads();
        if (wv == 0) {
            int s = (lane < 16) ? wsum[lane] : 0;
            #pragma unroll
            for (int off = 1; off < 16; off <<= 1) {
                int t = __shfl_up(s, off);
                if (lane >= off) s += t;
            }
            if (lane < 16) wsum[lane] = s;
        }
        __syncthreads();
        int carry = s_carry;
        int incl = carry + (wv ? wsum[wv - 1] : 0) + x;
        if (i < n) { indptr[i] = incl - v; cursor[i] = incl - v; }
        __syncthreads();
        if (tid == 0) s_carry = carry + wsum[15];
        // next chunk's first write to wsum happens after this iteration's
        // final barrier below (top of loop writes occur post-sync)
        __syncthreads();
    }
    if (tid == 0) indptr[n] = s_carry;
}

__global__ void scatter_kernel(const int* __restrict__ ei, int* __restrict__ cursor,
                               int* __restrict__ bucket) {
    int i = blockIdx.x * 256 + threadIdx.x;
    if (i < EE) {
        int d = ei[EE + i];
        int pos = atomicAdd(&cursor[d], 1);
        bucket[pos] = i;
    }
}

// ---------------- per-head attention constants + ea mean ----------------
__global__ void prep_kernel(const float* __restrict__ We1, const float* __restrict__ ae1,
                            const float* __restrict__ We2, const float* __restrict__ ae2,
                            float* __restrict__ consts) {
    int lane = threadIdx.x;
    if (lane < 4) {
        float s = 0.f;
        for (int c = 0; c < 32; c++) s += We1[lane * 32 + c] * ae1[lane * 32 + c];
        consts[2 + lane] = s;
    } else if (lane == 4) {
        float s = 0.f;
        for (int c = 0; c < 32; c++) s += We2[c] * ae2[c];
        consts[6] = s;
    } else if (lane == 5) {
        consts[1] = consts[0] / (float)EE;
    }
}

// ---------------- fp32 tiled GEMM: C[M,TN] = A[M,K] @ B[K,TN], bf16 or f32 out ----------------
template <int TM, int TN, int TK, int RM, int RN, bool BF16OUT>
__global__ __launch_bounds__(256) void gemm_kernel(const float* __restrict__ A,
                                                   const float* __restrict__ B,
                                                   void* __restrict__ Cv, int M, int K) {
    static_assert(TM * TN == 256 * RM * RN, "thread coverage");
    static_assert(RN % 2 == 0, "pairable");
    __shared__ float As[TK][TM + 4];
    __shared__ float Bs[TK][TN];
    int tid = threadIdx.x;
    int tx = tid % (TN / RN);
    int ty = tid / (TN / RN);
    int blockRow = blockIdx.x * TM;
    float acc[RM][RN];
    #pragma unroll
    for (int i = 0; i < RM; i++)
        #pragma unroll
        for (int j = 0; j < RN; j++) acc[i][j] = 0.f;

    for (int k0 = 0; k0 < K; k0 += TK) {
        #pragma unroll
        for (int l = 0; l < TM * TK; l += 256 * 4) {
            int ll = l + tid * 4;
            if (ll < TM * TK) {
                int r = ll / TK, kk = ll % TK;
                float4 v = make_float4(0.f, 0.f, 0.f, 0.f);
                int gr = blockRow + r;
                if (gr < M) v = *(const float4*)(A + (size_t)gr * K + k0 + kk);
                As[kk + 0][r] = v.x;
                As[kk + 1][r] = v.y;
                As[kk + 2][r] = v.z;
                As[kk + 3][r] = v.w;
            }
        }
        #pragma unroll
        for (int l = 0; l < TK * TN; l += 256 * 4) {
            int ll = l + tid * 4;
            if (ll < TK * TN) {
                int kk = ll / TN, c = ll % TN;
                *(float4*)&Bs[kk][c] = *(const float4*)(B + (size_t)(k0 + kk) * TN + c);
            }
        }
        __syncthreads();
        #pragma unroll
        for (int k = 0; k < TK; k++) {
            float af[RM], bf[RN];
            #pragma unroll
            for (int i = 0; i < RM; i++) af[i] = As[k][ty * RM + i];
            #pragma unroll
            for (int j = 0; j < RN; j++) bf[j] = Bs[k][tx * RN + j];
            #pragma unroll
            for (int i = 0; i < RM; i++)
                #pragma unroll
                for (int j = 0; j < RN; j++) acc[i][j] += af[i] * bf[j];
        }
        __syncthreads();
    }
    #pragma unroll
    for (int i = 0; i < RM; i++) {
        int gr = blockRow + ty * RM + i;
        if (gr < M) {
            if (BF16OUT) {
                unsigned short* C = (unsigned short*)Cv;
                #pragma unroll
                for (int j = 0; j < RN; j += 2) {
                    unsigned int pk = (unsigned int)f2bf(acc[i][j]) |
                                      ((unsigned int)f2bf(acc[i][j + 1]) << 16);
                    *(unsigned int*)(C + (size_t)gr * TN + tx * RN + j) = pk;
                }
            } else {
                float* C = (float*)Cv;
                #pragma unroll
                for (int j = 0; j < RN; j++) C[(size_t)gr * TN + tx * RN + j] = acc[i][j];
            }
        }
    }
}

// ---------------- attention logits per node (bf16 inputs) ----------------
__global__ void al1_kernel(const unsigned short* __restrict__ xs1b, const float* __restrict__ as1,
                           const float* __restrict__ ad1, float* __restrict__ als,
                           float* __restrict__ ald) {
    int t = blockIdx.x * 256 + threadIdx.x;
    if (t >= NN * 4) return;
    int h = t & 3;
    const unsigned int* xp = (const unsigned int*)(xs1b + (size_t)t * 32);
    const float* ap = as1 + h * 32;
    const float* dp = ad1 + h * 32;
    float s = 0.f, d = 0.f;
    #pragma unroll
    for (int q = 0; q < 16; q++) {
        float2 v = bf2f2(xp[q]);
        s += v.x * ap[q * 2] + v.y * ap[q * 2 + 1];
        d += v.x * dp[q * 2] + v.y * dp[q * 2 + 1];
    }
    als[t] = s;
    ald[t] = d;
}

__global__ void al2_kernel(const unsigned short* __restrict__ xs2b, const float* __restrict__ as2,
                           const float* __restrict__ ad2, float* __restrict__ als,
                           float* __restrict__ ald) {
    int t = blockIdx.x * 256 + threadIdx.x;
    if (t >= NN) return;
    const unsigned int* xp = (const unsigned int*)(xs2b + (size_t)t * 32);
    float s = 0.f, d = 0.f;
    #pragma unroll
    for (int q = 0; q < 16; q++) {
        float2 v = bf2f2(xp[q]);
        s += v.x * as2[q * 2] + v.y * as2[q * 2 + 1];
        d += v.x * ad2[q * 2] + v.y * ad2[q * 2 + 1];
    }
    als[t] = s;
    ald[t] = d;
}

// ---------------- conv1 aggregation: one wave per dst node (H=4, F=128, bf16 gather) ----------------
__global__ __launch_bounds__(256) void gat1_agg(
    const unsigned short* __restrict__ xs1b, const float* __restrict__ als,
    const float* __restrict__ ald, const int* __restrict__ ei, const float* __restrict__ ea,
    const int* __restrict__ indptr, const int* __restrict__ bucket,
    const float* __restrict__ consts, const float* __restrict__ b1,
    const float* __restrict__ g1, const float* __restrict__ be1, float* __restrict__ h1out) {
    __shared__ float exbuf[4][CAP1 * 4];
    __shared__ int srcbuf[4][CAP1];
    int wv = threadIdx.x >> 6;
    int lane = threadIdx.x & 63;
    int n = blockIdx.x * 4 + wv;
    if (n >= NN) return;
    int start = indptr[n];
    int deg = indptr[n + 1] - start;
    float ea_mean = consts[1];
    float ce[4] = {consts[2], consts[3], consts[4], consts[5]};
    float4 a4d = *(const float4*)(ald + (size_t)n * 4);
    float aldh[4] = {a4d.x, a4d.y, a4d.z, a4d.w};
    float4 a4s = *(const float4*)(als + (size_t)n * 4);
    float alsn[4] = {a4s.x, a4s.y, a4s.z, a4s.w};
    float asl[4], mx[4];
    #pragma unroll
    for (int h = 0; h < 4; h++) {
        float a = lrelu(alsn[h] + aldh[h] + ea_mean * ce[h]);
        asl[h] = a;
        mx[h] = a;
    }
    const int* bkt = bucket + start;
    // phase 1: alpha + max
    for (int i = lane; i < deg; i += 64) {
        int e = bkt[i];
        int s = ei[e];
        float eav = ea[e];
        float4 v4 = *(const float4*)(als + (size_t)s * 4);
        float alv[4] = {v4.x, v4.y, v4.z, v4.w};
        bool st = (i < CAP1);
        if (st) srcbuf[wv][i] = s;
        #pragma unroll
        for (int h = 0; h < 4; h++) {
            float a = lrelu(alv[h] + aldh[h] + eav * ce[h]);
            if (st) exbuf[wv][i * 4 + h] = a;
            mx[h] = fmaxf(mx[h], a);
        }
    }
    #pragma unroll
    for (int h = 0; h < 4; h++)
        for (int off = 32; off > 0; off >>= 1) mx[h] = fmaxf(mx[h], __shfl_xor(mx[h], off));
    // phase 2: sum of exp
    float sm[4] = {0.f, 0.f, 0.f, 0.f};
    for (int i = lane; i < deg; i += 64) {
        if (i < CAP1) {
            #pragma unroll
            for (int h = 0; h < 4; h++) {
                float exv = __expf(exbuf[wv][i * 4 + h] - mx[h]);
                exbuf[wv][i * 4 + h] = exv;
                sm[h] += exv;
            }
        } else {
            int e = bkt[i];
            int s = ei[e];
            float eav = ea[e];
            float4 v4 = *(const float4*)(als + (size_t)s * 4);
            float alv[4] = {v4.x, v4.y, v4.z, v4.w};
            #pragma unroll
            for (int h = 0; h < 4; h++) {
                float a = lrelu(alv[h] + aldh[h] + eav * ce[h]);
                sm[h] += __expf(a - mx[h]);
            }
        }
    }
    #pragma unroll
    for (int h = 0; h < 4; h++)
        for (int off = 32; off > 0; off >>= 1) sm[h] += __shfl_xor(sm[h], off);
    float inv[4];
    #pragma unroll
    for (int h = 0; h < 4; h++) inv[h] = 1.0f / (sm[h] + __expf(asl[h] - mx[h]) + 1e-16f);
    // phase 3: weighted gather (bf16); lane holds features c, c+1
    int c = lane * 2;
    int h = lane >> 4;
    float winv = inv[h];
    float wsl = __expf(asl[h] - mx[h]) * winv;
    float2 vself = bf2f2(*(const unsigned int*)(xs1b + (size_t)n * HC + c));
    float accx = vself.x * wsl, accy = vself.y * wsl;
    int m = deg < CAP1 ? deg : CAP1;
    int i = 0;
    for (; i + 4 <= m; i += 4) {
        float w0 = exbuf[wv][(i + 0) * 4 + h] * winv;
        float w1 = exbuf[wv][(i + 1) * 4 + h] * winv;
        float w2 = exbuf[wv][(i + 2) * 4 + h] * winv;
        float w3 = exbuf[wv][(i + 3) * 4 + h] * winv;
        int s0 = srcbuf[wv][i + 0], s1 = srcbuf[wv][i + 1];
        int s2 = srcbuf[wv][i + 2], s3 = srcbuf[wv][i + 3];
        float2 v0 = bf2f2(*(const unsigned int*)(xs1b + (size_t)s0 * HC + c));
        float2 v1 = bf2f2(*(const unsigned int*)(xs1b + (size_t)s1 * HC + c));
        float2 v2 = bf2f2(*(const unsigned int*)(xs1b + (size_t)s2 * HC + c));
        float2 v3 = bf2f2(*(const unsigned int*)(xs1b + (size_t)s3 * HC + c));
        accx += v0.x * w0; accy += v0.y * w0;
        accx += v1.x * w1; accy += v1.y * w1;
        accx += v2.x * w2; accy += v2.y * w2;
        accx += v3.x * w3; accy += v3.y * w3;
    }
    for (; i < m; i++) {
        float w0 = exbuf[wv][i * 4 + h] * winv;
        int s0 = srcbuf[wv][i];
        float2 v0 = bf2f2(*(const unsigned int*)(xs1b + (size_t)s0 * HC + c));
        accx += v0.x * w0; accy += v0.y * w0;
    }
    for (; i < deg; i++) {  // LDS-spill fallback (deg > CAP1): recompute
        int e = bkt[i];
        int s = ei[e];
        float eav = ea[e];
        float a = lrelu(als[(size_t)s * 4 + h] + aldh[h] + eav * ce[h]);
        float w0 = __expf(a - mx[h]) * winv;
        float2 v0 = bf2f2(*(const unsigned int*)(xs1b + (size_t)s * HC + c));
        accx += v0.x * w0; accy += v0.y * w0;
    }
    // epilogue: +bias, bn(eval), elu
    float o0 = accx + b1[c];
    float o1 = accy + b1[c + 1];
    o0 = o0 * (g1[c] * BN_RS) + be1[c];
    o1 = o1 * (g1[c + 1] * BN_RS) + be1[c + 1];
    o0 = elu(o0);
    o1 = elu(o1);
    *(float2*)(h1out + (size_t)n * HC + c) = make_float2(o0, o1);
}

// ---------------- conv2 aggregation: one wave per dst node (H=1, F=32, bf16 gather) ----------------
__global__ __launch_bounds__(256) void gat2_agg(
    const unsigned short* __restrict__ xs2b, const float* __restrict__ als,
    const float* __restrict__ ald, const int* __restrict__ ei, const float* __restrict__ ea,
    const int* __restrict__ indptr, const int* __restrict__ bucket,
    const float* __restrict__ consts, const float* __restrict__ b2,
    const float* __restrict__ g2, const float* __restrict__ be2, float* __restrict__ hout) {
    __shared__ float exbuf[4][CAP2];
    __shared__ int srcbuf[4][CAP2];
    int wv = threadIdx.x >> 6;
    int lane = threadIdx.x & 63;
    int n = blockIdx.x * 4 + wv;
    if (n >= NN) return;
    int start = indptr[n];
    int deg = indptr[n + 1] - start;
    float ea_mean = consts[1];
    float ce = consts[6];
    float aldn = ald[n];
    float a0 = lrelu(als[n] + aldn + ea_mean * ce);
    float mx = a0;
    const int* bkt = bucket + start;
    for (int i = lane; i < deg; i += 64) {
        int e = bkt[i];
        int s = ei[e];
        float eav = ea[e];
        float a = lrelu(als[s] + aldn + eav * ce);
        if (i < CAP2) { srcbuf[wv][i] = s; exbuf[wv][i] = a; }
        mx = fmaxf(mx, a);
    }
    for (int off = 32; off > 0; off >>= 1) mx = fmaxf(mx, __shfl_xor(mx, off));
    float sm = 0.f;
    for (int i = lane; i < deg; i += 64) {
        if (i < CAP2) {
            float exv = __expf(exbuf[wv][i] - mx);
            exbuf[wv][i] = exv;
            sm += exv;
        } else {
            int e = bkt[i];
            int s = ei[e];
            float eav = ea[e];
            float a = lrelu(als[s] + aldn + eav * ce);
            sm += __expf(a - mx);
        }
    }
    for (int off = 32; off > 0; off >>= 1) sm += __shfl_xor(sm, off);
    float invd = 1.0f / (sm + __expf(a0 - mx) + 1e-16f);
    // phase 3: 4 edges in parallel; 16 lanes/edge, 2 features per lane (bf16x2 = 4B)
    int quarter = lane >> 4;
    int cl = lane & 15;
    int c = cl * 2;
    float accx = 0.f, accy = 0.f;
    if (quarter == 0) {
        float2 vs = bf2f2(*(const unsigned int*)(xs2b + (size_t)n * CD + c));
        float wsl = __expf(a0 - mx) * invd;
        accx = vs.x * wsl; accy = vs.y * wsl;
    }
    int m = deg < CAP2 ? deg : CAP2;
    for (int i = quarter; i < m; i += 4) {
        float w0 = exbuf[wv][i] * invd;
        int s0 = srcbuf[wv][i];
        float2 v0 = bf2f2(*(const unsigned int*)(xs2b + (size_t)s0 * CD + c));
        accx += v0.x * w0; accy += v0.y * w0;
    }
    for (int i = CAP2 + quarter; i < deg; i += 4) {  // spill fallback
        int e = bkt[i];
        int s = ei[e];
        float eav = ea[e];
        float a = lrelu(als[s] + aldn + eav * ce);
        float w0 = __expf(a - mx) * invd;
        float2 v0 = bf2f2(*(const unsigned int*)(xs2b + (size_t)s * CD + c));
        accx += v0.x * w0; accy += v0.y * w0;
    }
    accx += __shfl_xor(accx, 16); accy += __shfl_xor(accy, 16);
    accx += __shfl_xor(accx, 32); accy += __shfl_xor(accy, 32);
    if (lane < 16) {
        float o0 = accx + b2[c];
        float o1 = accy + b2[c + 1];
        o0 = o0 * (g2[c] * BN_RS) + be2[c];
        o1 = o1 * (g2[c + 1] * BN_RS) + be2[c + 1];
        o0 = elu(o0);
        o1 = elu(o1);
        *(float2*)(hout + (size_t)n * CD + c) = make_float2(o0, o1);
    }
}

// ---------------- classifier + regressor heads ----------------
__global__ __launch_bounds__(256) void head_kernel(
    const float* __restrict__ h2, const float* __restrict__ Wc1, const float* __restrict__ bc1,
    const float* __restrict__ Wc2, const float* __restrict__ bc2,
    const float* __restrict__ Wr1, const float* __restrict__ br1,
    const float* __restrict__ Wr2, const float* __restrict__ br2,
    float* __restrict__ cls, float* __restrict__ reg) {
    int n = blockIdx.x * 256 + threadIdx.x;
    if (n >= NN) return;
    float hv[32];
    const float4* hp = (const float4*)(h2 + (size_t)n * 32);
    #pragma unroll
    for (int q = 0; q < 8; q++) {
        float4 t = hp[q];
        hv[q * 4] = t.x; hv[q * 4 + 1] = t.y; hv[q * 4 + 2] = t.z; hv[q * 4 + 3] = t.w;
    }
    float c0 = bc2[0], c1 = bc2[1];
    #pragma unroll
    for (int j = 0; j < 16; j++) {
        float s = bc1[j];
        #pragma unroll
        for (int cc = 0; cc < 32; cc++) s += hv[cc] * Wc1[cc * 16 + j];
        s = fmaxf(s, 0.f);
        c0 += s * Wc2[j * 2];
        c1 += s * Wc2[j * 2 + 1];
    }
    *(float2*)(cls + (size_t)n * 2) = make_float2(c0, c1);
    float r = br2[0];
    #pragma unroll
    for (int j = 0; j < 16; j++) {
        float s = br1[j];
        #pragma unroll
        for (int cc = 0; cc < 32; cc++) s += hv[cc] * Wr1[cc * 16 + j];
        s = fmaxf(s, 0.f);
        r += s * Wr2[j];
    }
    reg[n] = r;
}

// ---------------- launch ----------------
extern "C" void kernel_launch(void* const* d_in, const int* in_sizes, int n_in,
                              void* d_out, int out_size, void* d_ws, size_t ws_size,
                              hipStream_t stream) {
    const float* x   = (const float*)d_in[0];
    const int*   ei  = (const int*)d_in[1];
    const float* ea  = (const float*)d_in[2];
    const float* W1  = (const float*)d_in[3];
    const float* as1 = (const float*)d_in[4];
    const float* ad1 = (const float*)d_in[5];
    const float* We1 = (const float*)d_in[6];
    const float* ae1 = (const float*)d_in[7];
    const float* b1  = (const float*)d_in[8];
    const float* g1  = (const float*)d_in[9];
    const float* be1 = (const float*)d_in[10];
    const float* W2  = (const float*)d_in[11];
    const float* as2 = (const float*)d_in[12];
    const float* ad2 = (const float*)d_in[13];
    const float* We2 = (const float*)d_in[14];
    const float* ae2 = (const float*)d_in[15];
    const float* b2  = (const float*)d_in[16];
    const float* g2  = (const float*)d_in[17];
    const float* be2 = (const float*)d_in[18];
    const float* Wc1 = (const float*)d_in[19];
    const float* bc1 = (const float*)d_in[20];
    const float* Wc2 = (const float*)d_in[21];
    const float* bc2 = (const float*)d_in[22];
    const float* Wr1 = (const float*)d_in[23];
    const float* br1 = (const float*)d_in[24];
    const float* Wr2 = (const float*)d_in[25];
    const float* br2 = (const float*)d_in[26];

    char* ws = (char*)d_ws;
    unsigned short* xs1b = (unsigned short*)(ws + 0);         // N*128 bf16 = 12.8 MB
    float* h1            = (float*)(ws + 12800000);           // N*128 f32 = 25.6 MB
    unsigned short* xs2b = (unsigned short*)(ws + 38400000);  // N*32 bf16 = 3.2 MB
    float* als1          = (float*)(ws + 41600000);           // N*4
    float* ald1          = (float*)(ws + 42400000);           // N*4
    float* als2          = (float*)(ws + 43200000);           // N
    float* ald2          = (float*)(ws + 43400000);           // N
    float* consts        = (float*)(ws + 43600000);           // 8 floats
    int*   counts        = (int*)(ws + 43600128);             // N
    int*   indptr        = (int*)(ws + 43800128);             // N+1
    int*   cursor        = (int*)(ws + 44000160);             // N
    int*   bucket        = (int*)(ws + 44200160);             // E (ends ~50.6 MB)

    float* out_cls = (float*)d_out;            // [N,2]
    float* out_reg = out_cls + 2 * NN;         // [N]
    float* out_h   = out_cls + 3 * NN;         // [N,32]

    hipMemsetAsync(counts, 0, NN * sizeof(int), stream);
    hipMemsetAsync(consts, 0, 8 * sizeof(float), stream);

    // edge mean + CSR build
    ea_sum_kernel<<<256, 256, 0, stream>>>(ea, consts);
    count_kernel<<<(EE + 255) / 256, 256, 0, stream>>>(ei, counts);
    scan_kernel<<<1, 1024, 0, stream>>>(counts, indptr, cursor, NN);
    scatter_kernel<<<(EE + 255) / 256, 256, 0, stream>>>(ei, cursor, bucket);
    prep_kernel<<<1, 64, 0, stream>>>(We1, ae1, We2, ae2, consts);

    // conv1
    gemm_kernel<64, 128, 32, 4, 8, true><<<(NN + 63) / 64, 256, 0, stream>>>(x, W1, xs1b, NN, IN_DIM);
    al1_kernel<<<(NN * 4 + 255) / 256, 256, 0, stream>>>(xs1b, as1, ad1, als1, ald1);
    gat1_agg<<<(NN + 3) / 4, 256, 0, stream>>>(xs1b, als1, ald1, ei, ea, indptr, bucket,
                                               consts, b1, g1, be1, h1);
    // conv2
    gemm_kernel<128, 32, 32, 8, 2, true><<<(NN + 127) / 128, 256, 0, stream>>>(h1, W2, xs2b, NN, HC);
    al2_kernel<<<(NN + 255) / 256, 256, 0, stream>>>(xs2b, as2, ad2, als2, ald2);
    gat2_agg<<<(NN + 3) / 4, 256, 0, stream>>>(xs2b, als2, ald2, ei, ea, indptr, bucket,
                                               consts, b2, g2, be2, out_h);
    // heads
    head_kernel<<<(NN + 255) / 256, 256, 0, stream>>>(out_h, Wc1, bc1, Wc2, bc2,
                                                      Wr1, br1, Wr2, br2, out_cls, out_reg);
}

// Round 3
// 549.557 us; speedup vs baseline: 1.5770x; 1.3835x over previous
//
#include <hip/hip_runtime.h>
#include <cstdint>
#include <cstddef>

// ---------------- problem constants ----------------
#define NN 50000
#define EE 1600000
#define IN_DIM 256
#define HC 128      // HEADS*C
#define CD 32       // C
#define BN_RS 0.9999950000374997f  // 1/sqrt(1+1e-5)

#define CAP1 128
#define CAP2 128

// ---------------- small helpers ----------------
__device__ __forceinline__ float lrelu(float a) { return a > 0.f ? a : 0.2f * a; }
__device__ __forceinline__ float elu(float a) { return a > 0.f ? a : (__expf(a) - 1.f); }

// bf16 (stored as ushort bits) <-> f32
__device__ __forceinline__ unsigned short f2bf(float f) {
    unsigned int u = __float_as_uint(f);
    unsigned int r = (u + 0x7FFFu + ((u >> 16) & 1u)) >> 16;
    return (unsigned short)r;
}
__device__ __forceinline__ float2 bf2f2(unsigned int p) {
    float2 r;
    r.x = __uint_as_float(p << 16);
    r.y = __uint_as_float(p & 0xFFFF0000u);
    return r;
}
__device__ __forceinline__ void unpack_edge(unsigned long long p, int& s, float& eav) {
    s = (int)(unsigned int)(p & 0xFFFFFFFFull);
    eav = __uint_as_float((unsigned int)(p >> 32));
}

// ---------------- count (8 edges/thread ILP) + fused ea-sum ----------------
__global__ __launch_bounds__(256) void count_kernel(const int* __restrict__ ei,
                                                    const float* __restrict__ ea,
                                                    int* __restrict__ counts,
                                                    float* __restrict__ easum) {
    int base = blockIdx.x * 2048 + threadIdx.x;
    float s = 0.f;
    #pragma unroll
    for (int k = 0; k < 8; k++) {
        int i = base + k * 256;
        if (i < EE) {
            atomicAdd(&counts[ei[EE + i]], 1);
            s += ea[i];
        }
    }
    #pragma unroll
    for (int off = 32; off > 0; off >>= 1) s += __shfl_xor(s, off);
    if ((threadIdx.x & 63) == 0) atomicAdd(easum, s);
}

// ---------------- hierarchical scan (3 tiny kernels) ----------------
__global__ __launch_bounds__(256) void scan_local(const int* __restrict__ counts,
                                                  int* __restrict__ localbuf,
                                                  int* __restrict__ partials, int n) {
    __shared__ int wsum[4];
    int tid = threadIdx.x, lane = tid & 63, wv = tid >> 6;
    int i = blockIdx.x * 1024 + tid * 4;
    int v0 = 0, v1 = 0, v2 = 0, v3 = 0;
    if (i < n) { int4 t = *(const int4*)(counts + i); v0 = t.x; v1 = t.y; v2 = t.z; v3 = t.w; }
    int t = v0 + v1 + v2 + v3;
    int x = t;
    #pragma unroll
    for (int off = 1; off < 64; off <<= 1) {
        int y = __shfl_up(x, off);
        if (lane >= off) x += y;
    }
    if (lane == 63) wsum[wv] = x;
    __syncthreads();
    int wpre = 0;
    #pragma unroll
    for (int w = 0; w < 4; w++)
        if (w < wv) wpre += wsum[w];
    if (i < n) {
        int e0 = wpre + x - t;
        int4 o;
        o.x = e0; o.y = e0 + v0; o.z = o.y + v1; o.w = o.z + v2;
        *(int4*)(localbuf + i) = o;
    }
    if (tid == 0) partials[blockIdx.x] = wsum[0] + wsum[1] + wsum[2] + wsum[3];
}

__global__ void scan_part(int* __restrict__ partials, int* __restrict__ indptr, int nblk) {
    int lane = threadIdx.x;  // 64 threads
    int v = (lane < nblk) ? partials[lane] : 0;
    int x = v;
    #pragma unroll
    for (int off = 1; off < 64; off <<= 1) {
        int y = __shfl_up(x, off);
        if (lane >= off) x += y;
    }
    if (lane < nblk) partials[lane] = x - v;
    if (lane == 0) indptr[NN] = EE;
}

__global__ __launch_bounds__(256) void scan_add(const int* __restrict__ localbuf,
                                                const int* __restrict__ partials,
                                                int* __restrict__ indptr,
                                                int* __restrict__ cursor, int n) {
    int i = blockIdx.x * 1024 + threadIdx.x * 4;
    if (i < n) {
        int off = partials[blockIdx.x];
        int4 t = *(const int4*)(localbuf + i);
        t.x += off; t.y += off; t.z += off; t.w += off;
        *(int4*)(indptr + i) = t;
        *(int4*)(cursor + i) = t;
    }
}

// ---------------- scatter (8 edges/thread ILP, packed {src,ea} payload) ----------------
__global__ __launch_bounds__(256) void scatter_kernel(const int* __restrict__ ei,
                                                      const float* __restrict__ ea,
                                                      int* __restrict__ cursor,
                                                      unsigned long long* __restrict__ edgedat) {
    int base = blockIdx.x * 2048 + threadIdx.x;
    int pos[8], src[8];
    float eav[8];
    #pragma unroll
    for (int k = 0; k < 8; k++) {
        int i = base + k * 256;
        if (i < EE) {
            src[k] = ei[i];
            eav[k] = ea[i];
            int d = ei[EE + i];
            pos[k] = atomicAdd(&cursor[d], 1);
        }
    }
    #pragma unroll
    for (int k = 0; k < 8; k++) {
        int i = base + k * 256;
        if (i < EE) {
            edgedat[pos[k]] = (unsigned long long)(unsigned int)src[k] |
                              ((unsigned long long)__float_as_uint(eav[k]) << 32);
        }
    }
}

// ---------------- per-head attention constants + ea mean ----------------
__global__ void prep_kernel(const float* __restrict__ We1, const float* __restrict__ ae1,
                            const float* __restrict__ We2, const float* __restrict__ ae2,
                            float* __restrict__ consts) {
    int lane = threadIdx.x;
    if (lane < 4) {
        float s = 0.f;
        for (int c = 0; c < 32; c++) s += We1[lane * 32 + c] * ae1[lane * 32 + c];
        consts[2 + lane] = s;
    } else if (lane == 4) {
        float s = 0.f;
        for (int c = 0; c < 32; c++) s += We2[c] * ae2[c];
        consts[6] = s;
    } else if (lane == 5) {
        consts[1] = consts[0] / (float)EE;
    }
}

// ---------------- fp32 tiled GEMM: C[M,TN] = A[M,K] @ B[K,TN], bf16 or f32 out ----------------
template <int TM, int TN, int TK, int RM, int RN, bool BF16OUT>
__global__ __launch_bounds__(256) void gemm_kernel(const float* __restrict__ A,
                                                   const float* __restrict__ B,
                                                   void* __restrict__ Cv, int M, int K) {
    static_assert(TM * TN == 256 * RM * RN, "thread coverage");
    static_assert(RN % 2 == 0, "pairable");
    __shared__ float As[TK][TM + 4];
    __shared__ float Bs[TK][TN];
    int tid = threadIdx.x;
    int tx = tid % (TN / RN);
    int ty = tid / (TN / RN);
    int blockRow = blockIdx.x * TM;
    float acc[RM][RN];
    #pragma unroll
    for (int i = 0; i < RM; i++)
        #pragma unroll
        for (int j = 0; j < RN; j++) acc[i][j] = 0.f;

    for (int k0 = 0; k0 < K; k0 += TK) {
        #pragma unroll
        for (int l = 0; l < TM * TK; l += 256 * 4) {
            int ll = l + tid * 4;
            if (ll < TM * TK) {
                int r = ll / TK, kk = ll % TK;
                float4 v = make_float4(0.f, 0.f, 0.f, 0.f);
                int gr = blockRow + r;
                if (gr < M) v = *(const float4*)(A + (size_t)gr * K + k0 + kk);
                As[kk + 0][r] = v.x;
                As[kk + 1][r] = v.y;
                As[kk + 2][r] = v.z;
                As[kk + 3][r] = v.w;
            }
        }
        #pragma unroll
        for (int l = 0; l < TK * TN; l += 256 * 4) {
            int ll = l + tid * 4;
            if (ll < TK * TN) {
                int kk = ll / TN, c = ll % TN;
                *(float4*)&Bs[kk][c] = *(const float4*)(B + (size_t)(k0 + kk) * TN + c);
            }
        }
        __syncthreads();
        #pragma unroll
        for (int k = 0; k < TK; k++) {
            float af[RM], bf[RN];
            #pragma unroll
            for (int i = 0; i < RM; i++) af[i] = As[k][ty * RM + i];
            #pragma unroll
            for (int j = 0; j < RN; j++) bf[j] = Bs[k][tx * RN + j];
            #pragma unroll
            for (int i = 0; i < RM; i++)
                #pragma unroll
                for (int j = 0; j < RN; j++) acc[i][j] += af[i] * bf[j];
        }
        __syncthreads();
    }
    #pragma unroll
    for (int i = 0; i < RM; i++) {
        int gr = blockRow + ty * RM + i;
        if (gr < M) {
            if (BF16OUT) {
                unsigned short* C = (unsigned short*)Cv;
                #pragma unroll
                for (int j = 0; j < RN; j += 2) {
                    unsigned int pk = (unsigned int)f2bf(acc[i][j]) |
                                      ((unsigned int)f2bf(acc[i][j + 1]) << 16);
                    *(unsigned int*)(C + (size_t)gr * TN + tx * RN + j) = pk;
                }
            } else {
                float* C = (float*)Cv;
                #pragma unroll
                for (int j = 0; j < RN; j++) C[(size_t)gr * TN + tx * RN + j] = acc[i][j];
            }
        }
    }
}

// ---------------- attention logits per node (bf16 inputs) ----------------
__global__ void al1_kernel(const unsigned short* __restrict__ xs1b, const float* __restrict__ as1,
                           const float* __restrict__ ad1, float* __restrict__ als,
                           float* __restrict__ ald) {
    int t = blockIdx.x * 256 + threadIdx.x;
    if (t >= NN * 4) return;
    int h = t & 3;
    const unsigned int* xp = (const unsigned int*)(xs1b + (size_t)t * 32);
    const float* ap = as1 + h * 32;
    const float* dp = ad1 + h * 32;
    float s = 0.f, d = 0.f;
    #pragma unroll
    for (int q = 0; q < 16; q++) {
        float2 v = bf2f2(xp[q]);
        s += v.x * ap[q * 2] + v.y * ap[q * 2 + 1];
        d += v.x * dp[q * 2] + v.y * dp[q * 2 + 1];
    }
    als[t] = s;
    ald[t] = d;
}

__global__ void al2_kernel(const unsigned short* __restrict__ xs2b, const float* __restrict__ as2,
                           const float* __restrict__ ad2, float* __restrict__ als,
                           float* __restrict__ ald) {
    int t = blockIdx.x * 256 + threadIdx.x;
    if (t >= NN) return;
    const unsigned int* xp = (const unsigned int*)(xs2b + (size_t)t * 32);
    float s = 0.f, d = 0.f;
    #pragma unroll
    for (int q = 0; q < 16; q++) {
        float2 v = bf2f2(xp[q]);
        s += v.x * as2[q * 2] + v.y * as2[q * 2 + 1];
        d += v.x * ad2[q * 2] + v.y * ad2[q * 2 + 1];
    }
    als[t] = s;
    ald[t] = d;
}

// ---------------- conv1 aggregation: one wave per dst node (H=4, F=128, bf16 gather) ----------------
__global__ __launch_bounds__(256) void gat1_agg(
    const unsigned short* __restrict__ xs1b, const float* __restrict__ als,
    const float* __restrict__ ald, const unsigned long long* __restrict__ edgedat,
    const int* __restrict__ indptr, const float* __restrict__ consts,
    const float* __restrict__ b1, const float* __restrict__ g1,
    const float* __restrict__ be1, float* __restrict__ h1out) {
    __shared__ float exbuf[4][CAP1 * 4];
    __shared__ int srcbuf[4][CAP1];
    int wv = threadIdx.x >> 6;
    int lane = threadIdx.x & 63;
    int n = blockIdx.x * 4 + wv;   // grid is exact: NN % 4 == 0
    int start = indptr[n];
    int deg = indptr[n + 1] - start;
    float ea_mean = consts[1];
    float ce[4] = {consts[2], consts[3], consts[4], consts[5]};
    float4 a4d = *(const float4*)(ald + (size_t)n * 4);
    float aldh[4] = {a4d.x, a4d.y, a4d.z, a4d.w};
    float4 a4s = *(const float4*)(als + (size_t)n * 4);
    float alsn[4] = {a4s.x, a4s.y, a4s.z, a4s.w};
    float asl[4], mx[4];
    #pragma unroll
    for (int h = 0; h < 4; h++) {
        float a = lrelu(alsn[h] + aldh[h] + ea_mean * ce[h]);
        asl[h] = a;
        mx[h] = a;
    }
    const unsigned long long* edp = edgedat + start;
    // phase 1: alpha + max
    for (int i = lane; i < deg; i += 64) {
        int s; float eav;
        unpack_edge(edp[i], s, eav);
        float4 v4 = *(const float4*)(als + (size_t)s * 4);
        float alv[4] = {v4.x, v4.y, v4.z, v4.w};
        bool st = (i < CAP1);
        if (st) srcbuf[wv][i] = s;
        #pragma unroll
        for (int h = 0; h < 4; h++) {
            float a = lrelu(alv[h] + aldh[h] + eav * ce[h]);
            if (st) exbuf[wv][i * 4 + h] = a;
            mx[h] = fmaxf(mx[h], a);
        }
    }
    #pragma unroll
    for (int h = 0; h < 4; h++)
        for (int off = 32; off > 0; off >>= 1) mx[h] = fmaxf(mx[h], __shfl_xor(mx[h], off));
    // phase 2: sum of exp (LDS-resident for deg<=CAP1, which is ~always)
    float sm[4] = {0.f, 0.f, 0.f, 0.f};
    for (int i = lane; i < deg; i += 64) {
        if (i < CAP1) {
            #pragma unroll
            for (int h = 0; h < 4; h++) {
                float exv = __expf(exbuf[wv][i * 4 + h] - mx[h]);
                exbuf[wv][i * 4 + h] = exv;
                sm[h] += exv;
            }
        } else {
            int s; float eav;
            unpack_edge(edp[i], s, eav);
            float4 v4 = *(const float4*)(als + (size_t)s * 4);
            float alv[4] = {v4.x, v4.y, v4.z, v4.w};
            #pragma unroll
            for (int h = 0; h < 4; h++) {
                float a = lrelu(alv[h] + aldh[h] + eav * ce[h]);
                sm[h] += __expf(a - mx[h]);
            }
        }
    }
    #pragma unroll
    for (int h = 0; h < 4; h++)
        for (int off = 32; off > 0; off >>= 1) sm[h] += __shfl_xor(sm[h], off);
    float inv[4];
    #pragma unroll
    for (int h = 0; h < 4; h++) inv[h] = 1.0f / (sm[h] + __expf(asl[h] - mx[h]) + 1e-16f);
    // phase 3: weighted gather (bf16); lane holds features c, c+1
    int c = lane * 2;
    int h = lane >> 4;
    float winv = inv[h];
    float wsl = __expf(asl[h] - mx[h]) * winv;
    float2 vself = bf2f2(*(const unsigned int*)(xs1b + (size_t)n * HC + c));
    float accx = vself.x * wsl, accy = vself.y * wsl;
    int m = deg < CAP1 ? deg : CAP1;
    int i = 0;
    for (; i + 4 <= m; i += 4) {
        float w0 = exbuf[wv][(i + 0) * 4 + h] * winv;
        float w1 = exbuf[wv][(i + 1) * 4 + h] * winv;
        float w2 = exbuf[wv][(i + 2) * 4 + h] * winv;
        float w3 = exbuf[wv][(i + 3) * 4 + h] * winv;
        int s0 = srcbuf[wv][i + 0], s1 = srcbuf[wv][i + 1];
        int s2 = srcbuf[wv][i + 2], s3 = srcbuf[wv][i + 3];
        float2 v0 = bf2f2(*(const unsigned int*)(xs1b + (size_t)s0 * HC + c));
        float2 v1 = bf2f2(*(const unsigned int*)(xs1b + (size_t)s1 * HC + c));
        float2 v2 = bf2f2(*(const unsigned int*)(xs1b + (size_t)s2 * HC + c));
        float2 v3 = bf2f2(*(const unsigned int*)(xs1b + (size_t)s3 * HC + c));
        accx += v0.x * w0; accy += v0.y * w0;
        accx += v1.x * w1; accy += v1.y * w1;
        accx += v2.x * w2; accy += v2.y * w2;
        accx += v3.x * w3; accy += v3.y * w3;
    }
    for (; i < m; i++) {
        float w0 = exbuf[wv][i * 4 + h] * winv;
        int s0 = srcbuf[wv][i];
        float2 v0 = bf2f2(*(const unsigned int*)(xs1b + (size_t)s0 * HC + c));
        accx += v0.x * w0; accy += v0.y * w0;
    }
    for (; i < deg; i++) {  // LDS-spill fallback (deg > CAP1): recompute
        int s; float eav;
        unpack_edge(edp[i], s, eav);
        float a = lrelu(als[(size_t)s * 4 + h] + aldh[h] + eav * ce[h]);
        float w0 = __expf(a - mx[h]) * winv;
        float2 v0 = bf2f2(*(const unsigned int*)(xs1b + (size_t)s * HC + c));
        accx += v0.x * w0; accy += v0.y * w0;
    }
    // epilogue: +bias, bn(eval), elu
    float o0 = accx + b1[c];
    float o1 = accy + b1[c + 1];
    o0 = o0 * (g1[c] * BN_RS) + be1[c];
    o1 = o1 * (g1[c + 1] * BN_RS) + be1[c + 1];
    o0 = elu(o0);
    o1 = elu(o1);
    *(float2*)(h1out + (size_t)n * HC + c) = make_float2(o0, o1);
}

// ---------------- conv2 aggregation + fused MLP heads ----------------
__global__ __launch_bounds__(256) void gat2_agg(
    const unsigned short* __restrict__ xs2b, const float* __restrict__ als,
    const float* __restrict__ ald, const unsigned long long* __restrict__ edgedat,
    const int* __restrict__ indptr, const float* __restrict__ consts,
    const float* __restrict__ b2, const float* __restrict__ g2, const float* __restrict__ be2,
    const float* __restrict__ Wc1, const float* __restrict__ bc1,
    const float* __restrict__ Wc2, const float* __restrict__ bc2,
    const float* __restrict__ Wr1, const float* __restrict__ br1,
    const float* __restrict__ Wr2, const float* __restrict__ br2,
    float* __restrict__ hout, float* __restrict__ cls, float* __restrict__ reg) {
    __shared__ float exbuf[4][CAP2];
    __shared__ int srcbuf[4][CAP2];
    __shared__ float hbuf[4][32];
    int wv = threadIdx.x >> 6;
    int lane = threadIdx.x & 63;
    int n = blockIdx.x * 4 + wv;   // grid exact
    int start = indptr[n];
    int deg = indptr[n + 1] - start;
    float ea_mean = consts[1];
    float ce = consts[6];
    float aldn = ald[n];
    float a0 = lrelu(als[n] + aldn + ea_mean * ce);
    float mx = a0;
    const unsigned long long* edp = edgedat + start;
    for (int i = lane; i < deg; i += 64) {
        int s; float eav;
        unpack_edge(edp[i], s, eav);
        float a = lrelu(als[s] + aldn + eav * ce);
        if (i < CAP2) { srcbuf[wv][i] = s; exbuf[wv][i] = a; }
        mx = fmaxf(mx, a);
    }
    for (int off = 32; off > 0; off >>= 1) mx = fmaxf(mx, __shfl_xor(mx, off));
    float sm = 0.f;
    for (int i = lane; i < deg; i += 64) {
        if (i < CAP2) {
            float exv = __expf(exbuf[wv][i] - mx);
            exbuf[wv][i] = exv;
            sm += exv;
        } else {
            int s; float eav;
            unpack_edge(edp[i], s, eav);
            float a = lrelu(als[s] + aldn + eav * ce);
            sm += __expf(a - mx);
        }
    }
    for (int off = 32; off > 0; off >>= 1) sm += __shfl_xor(sm, off);
    float invd = 1.0f / (sm + __expf(a0 - mx) + 1e-16f);
    // phase 3: 4 edges in parallel; 16 lanes/edge, 2 features per lane (bf16x2 = 4B)
    int quarter = lane >> 4;
    int cl = lane & 15;
    int c = cl * 2;
    float accx = 0.f, accy = 0.f;
    if (quarter == 0) {
        float2 vs = bf2f2(*(const unsigned int*)(xs2b + (size_t)n * CD + c));
        float wsl = __expf(a0 - mx) * invd;
        accx = vs.x * wsl; accy = vs.y * wsl;
    }
    int m = deg < CAP2 ? deg : CAP2;
    for (int i = quarter; i < m; i += 4) {
        float w0 = exbuf[wv][i] * invd;
        int s0 = srcbuf[wv][i];
        float2 v0 = bf2f2(*(const unsigned int*)(xs2b + (size_t)s0 * CD + c));
        accx += v0.x * w0; accy += v0.y * w0;
    }
    for (int i = CAP2 + quarter; i < deg; i += 4) {  // spill fallback
        int s; float eav;
        unpack_edge(edp[i], s, eav);
        float a = lrelu(als[s] + aldn + eav * ce);
        float w0 = __expf(a - mx) * invd;
        float2 v0 = bf2f2(*(const unsigned int*)(xs2b + (size_t)s * CD + c));
        accx += v0.x * w0; accy += v0.y * w0;
    }
    accx += __shfl_xor(accx, 16); accy += __shfl_xor(accy, 16);
    accx += __shfl_xor(accx, 32); accy += __shfl_xor(accy, 32);
    if (lane < 16) {
        float o0 = accx + b2[c];
        float o1 = accy + b2[c + 1];
        o0 = o0 * (g2[c] * BN_RS) + be2[c];
        o1 = o1 * (g2[c + 1] * BN_RS) + be2[c + 1];
        o0 = elu(o0);
        o1 = elu(o1);
        hbuf[wv][c] = o0;
        hbuf[wv][c + 1] = o1;
        *(float2*)(hout + (size_t)n * CD + c) = make_float2(o0, o1);
    }
    __syncthreads();
    // fused heads: lanes 0-15 classifier hidden unit j, lanes 16-31 regressor hidden unit j
    float r0 = 0.f, r1 = 0.f;
    if (lane < 32) {
        int j = lane & 15;
        bool iscls = lane < 16;
        float s = iscls ? bc1[j] : br1[j];
        #pragma unroll
        for (int cc = 0; cc < 32; cc++) {
            float w = iscls ? Wc1[cc * 16 + j] : Wr1[cc * 16 + j];
            s += hbuf[wv][cc] * w;
        }
        s = fmaxf(s, 0.f);
        if (iscls) { r0 = s * Wc2[j * 2]; r1 = s * Wc2[j * 2 + 1]; }
        else       { r0 = s * Wr2[j]; }
    }
    #pragma unroll
    for (int off = 1; off < 16; off <<= 1) {
        r0 += __shfl_xor(r0, off);
        r1 += __shfl_xor(r1, off);
    }
    if (lane == 0)  *(float2*)(cls + (size_t)n * 2) = make_float2(r0 + bc2[0], r1 + bc2[1]);
    if (lane == 16) reg[n] = r0 + br2[0];
}

// ---------------- launch ----------------
extern "C" void kernel_launch(void* const* d_in, const int* in_sizes, int n_in,
                              void* d_out, int out_size, void* d_ws, size_t ws_size,
                              hipStream_t stream) {
    const float* x   = (const float*)d_in[0];
    const int*   ei  = (const int*)d_in[1];
    const float* ea  = (const float*)d_in[2];
    const float* W1  = (const float*)d_in[3];
    const float* as1 = (const float*)d_in[4];
    const float* ad1 = (const float*)d_in[5];
    const float* We1 = (const float*)d_in[6];
    const float* ae1 = (const float*)d_in[7];
    const float* b1  = (const float*)d_in[8];
    const float* g1  = (const float*)d_in[9];
    const float* be1 = (const float*)d_in[10];
    const float* W2  = (const float*)d_in[11];
    const float* as2 = (const float*)d_in[12];
    const float* ad2 = (const float*)d_in[13];
    const float* We2 = (const float*)d_in[14];
    const float* ae2 = (const float*)d_in[15];
    const float* b2  = (const float*)d_in[16];
    const float* g2  = (const float*)d_in[17];
    const float* be2 = (const float*)d_in[18];
    const float* Wc1 = (const float*)d_in[19];
    const float* bc1 = (const float*)d_in[20];
    const float* Wc2 = (const float*)d_in[21];
    const float* bc2 = (const float*)d_in[22];
    const float* Wr1 = (const float*)d_in[23];
    const float* br1 = (const float*)d_in[24];
    const float* Wr2 = (const float*)d_in[25];
    const float* br2 = (const float*)d_in[26];

    char* ws = (char*)d_ws;
    unsigned short* xs1b = (unsigned short*)(ws + 0);          // N*128 bf16 = 12.8 MB
    float* h1            = (float*)(ws + 12800000);            // N*128 f32 = 25.6 MB
    unsigned short* xs2b = (unsigned short*)(ws + 38400000);   // N*32 bf16 = 3.2 MB
    float* als1          = (float*)(ws + 41600000);            // N*4
    float* ald1          = (float*)(ws + 42400000);            // N*4
    float* als2          = (float*)(ws + 43200000);            // N
    float* ald2          = (float*)(ws + 43400000);            // N
    float* consts        = (float*)(ws + 43600000);            // 8 floats
    int*   counts        = (int*)(ws + 43600128);              // N
    int*   indptr        = (int*)(ws + 43800128);              // N+1 (padded)
    int*   cursor        = (int*)(ws + 44000136);              // N
    int*   partials      = (int*)(ws + 44200136);              // 64
    int*   localbuf      = (int*)(ws + 44200400);              // N
    unsigned long long* edgedat = (unsigned long long*)(ws + 44400400);  // E*8 = 12.8 MB (ends ~57.2 MB)

    float* out_cls = (float*)d_out;            // [N,2]
    float* out_reg = out_cls + 2 * NN;         // [N]
    float* out_h   = out_cls + 3 * NN;         // [N,32]

    hipMemsetAsync(counts, 0, NN * sizeof(int), stream);
    hipMemsetAsync(consts, 0, 8 * sizeof(float), stream);

    // CSR build + edge mean
    count_kernel<<<(EE + 2047) / 2048, 256, 0, stream>>>(ei, ea, counts, consts);
    scan_local<<<(NN + 1023) / 1024, 256, 0, stream>>>(counts, localbuf, partials, NN);
    scan_part<<<1, 64, 0, stream>>>(partials, indptr, (NN + 1023) / 1024);
    scan_add<<<(NN + 1023) / 1024, 256, 0, stream>>>(localbuf, partials, indptr, cursor, NN);
    scatter_kernel<<<(EE + 2047) / 2048, 256, 0, stream>>>(ei, ea, cursor, edgedat);
    prep_kernel<<<1, 64, 0, stream>>>(We1, ae1, We2, ae2, consts);

    // conv1
    gemm_kernel<64, 128, 32, 4, 8, true><<<(NN + 63) / 64, 256, 0, stream>>>(x, W1, xs1b, NN, IN_DIM);
    al1_kernel<<<(NN * 4 + 255) / 256, 256, 0, stream>>>(xs1b, as1, ad1, als1, ald1);
    gat1_agg<<<NN / 4, 256, 0, stream>>>(xs1b, als1, ald1, edgedat, indptr, consts,
                                         b1, g1, be1, h1);
    // conv2
    gemm_kernel<128, 32, 32, 8, 2, true><<<(NN + 127) / 128, 256, 0, stream>>>(h1, W2, xs2b, NN, HC);
    al2_kernel<<<(NN + 255) / 256, 256, 0, stream>>>(xs2b, as2, ad2, als2, ald2);
    gat2_agg<<<NN / 4, 256, 0, stream>>>(xs2b, als2, ald2, edgedat, indptr, consts,
                                         b2, g2, be2, Wc1, bc1, Wc2, bc2,
                                         Wr1, br1, Wr2, br2, out_h, out_cls, out_reg);
}

// Round 4
// 491.115 us; speedup vs baseline: 1.7647x; 1.1190x over previous
//
#include <hip/hip_runtime.h>
#include <cstdint>
#include <cstddef>

// ---------------- problem constants ----------------
#define NN 50000
#define EE 1600000
#define IN_DIM 256
#define HC 128      // HEADS*C
#define CD 32       // C
#define BN_RS 0.9999950000374997f  // 1/sqrt(1+1e-5)

#define CAP1 128
#define CAP2 128

// ---------------- small helpers ----------------
__device__ __forceinline__ float lrelu(float a) { return a > 0.f ? a : 0.2f * a; }
__device__ __forceinline__ float elu(float a) { return a > 0.f ? a : (__expf(a) - 1.f); }

// bf16 (stored as ushort bits) <-> f32
__device__ __forceinline__ unsigned short f2bf(float f) {
    unsigned int u = __float_as_uint(f);
    unsigned int r = (u + 0x7FFFu + ((u >> 16) & 1u)) >> 16;
    return (unsigned short)r;
}
__device__ __forceinline__ float2 bf2f2(unsigned int p) {
    float2 r;
    r.x = __uint_as_float(p << 16);
    r.y = __uint_as_float(p & 0xFFFF0000u);
    return r;
}
__device__ __forceinline__ void unpack_edge(unsigned long long p, int& s, float& eav) {
    s = (int)(unsigned int)(p & 0xFFFFFFFFull);
    eav = __uint_as_float((unsigned int)(p >> 32));
}

// ---------------- count (8 edges/thread) + rank capture + fused ea-sum ----------------
// atomicAdd's return value IS the edge's unique rank within its dst bucket;
// storing it (coalesced) lets the scatter pass run atomic-free.
__global__ __launch_bounds__(256) void count_kernel(const int* __restrict__ ei,
                                                    const float* __restrict__ ea,
                                                    int* __restrict__ counts,
                                                    int* __restrict__ rank,
                                                    float* __restrict__ easum) {
    int base = blockIdx.x * 2048 + threadIdx.x;
    float s = 0.f;
    #pragma unroll
    for (int k = 0; k < 8; k++) {
        int i = base + k * 256;
        if (i < EE) {
            int r = atomicAdd(&counts[ei[EE + i]], 1);
            rank[i] = r;
            s += ea[i];
        }
    }
    #pragma unroll
    for (int off = 32; off > 0; off >>= 1) s += __shfl_xor(s, off);
    if ((threadIdx.x & 63) == 0) atomicAdd(easum, s);
}

// ---------------- hierarchical scan (3 tiny kernels) ----------------
__global__ __launch_bounds__(256) void scan_local(const int* __restrict__ counts,
                                                  int* __restrict__ localbuf,
                                                  int* __restrict__ partials, int n) {
    __shared__ int wsum[4];
    int tid = threadIdx.x, lane = tid & 63, wv = tid >> 6;
    int i = blockIdx.x * 1024 + tid * 4;
    int v0 = 0, v1 = 0, v2 = 0, v3 = 0;
    if (i < n) { int4 t = *(const int4*)(counts + i); v0 = t.x; v1 = t.y; v2 = t.z; v3 = t.w; }
    int t = v0 + v1 + v2 + v3;
    int x = t;
    #pragma unroll
    for (int off = 1; off < 64; off <<= 1) {
        int y = __shfl_up(x, off);
        if (lane >= off) x += y;
    }
    if (lane == 63) wsum[wv] = x;
    __syncthreads();
    int wpre = 0;
    #pragma unroll
    for (int w = 0; w < 4; w++)
        if (w < wv) wpre += wsum[w];
    if (i < n) {
        int e0 = wpre + x - t;
        int4 o;
        o.x = e0; o.y = e0 + v0; o.z = o.y + v1; o.w = o.z + v2;
        *(int4*)(localbuf + i) = o;
    }
    if (tid == 0) partials[blockIdx.x] = wsum[0] + wsum[1] + wsum[2] + wsum[3];
}

__global__ void scan_part(int* __restrict__ partials, int* __restrict__ indptr, int nblk) {
    int lane = threadIdx.x;  // 64 threads
    int v = (lane < nblk) ? partials[lane] : 0;
    int x = v;
    #pragma unroll
    for (int off = 1; off < 64; off <<= 1) {
        int y = __shfl_up(x, off);
        if (lane >= off) x += y;
    }
    if (lane < nblk) partials[lane] = x - v;
    if (lane == 0) indptr[NN] = EE;
}

__global__ __launch_bounds__(256) void scan_add(const int* __restrict__ localbuf,
                                                const int* __restrict__ partials,
                                                int* __restrict__ indptr, int n) {
    int i = blockIdx.x * 1024 + threadIdx.x * 4;
    if (i < n) {
        int off = partials[blockIdx.x];
        int4 t = *(const int4*)(localbuf + i);
        t.x += off; t.y += off; t.z += off; t.w += off;
        *(int4*)(indptr + i) = t;
    }
}

// ---------------- scatter: atomic-free, pos = indptr[dst] + rank[e] ----------------
// indptr is 200 KB -> L2-resident; payload store is fire-and-forget.
__global__ __launch_bounds__(256) void scatter_kernel(const int* __restrict__ ei,
                                                      const float* __restrict__ ea,
                                                      const int* __restrict__ rank,
                                                      const int* __restrict__ indptr,
                                                      unsigned long long* __restrict__ edgedat) {
    int base = blockIdx.x * 2048 + threadIdx.x;
    #pragma unroll
    for (int k = 0; k < 8; k++) {
        int i = base + k * 256;
        if (i < EE) {
            int src = ei[i];
            int d = ei[EE + i];
            float eav = ea[i];
            int pos = indptr[d] + rank[i];
            edgedat[pos] = (unsigned long long)(unsigned int)src |
                           ((unsigned long long)__float_as_uint(eav) << 32);
        }
    }
}

// ---------------- per-head attention constants + ea mean ----------------
__global__ void prep_kernel(const float* __restrict__ We1, const float* __restrict__ ae1,
                            const float* __restrict__ We2, const float* __restrict__ ae2,
                            float* __restrict__ consts) {
    int lane = threadIdx.x;
    if (lane < 4) {
        float s = 0.f;
        for (int c = 0; c < 32; c++) s += We1[lane * 32 + c] * ae1[lane * 32 + c];
        consts[2 + lane] = s;
    } else if (lane == 4) {
        float s = 0.f;
        for (int c = 0; c < 32; c++) s += We2[c] * ae2[c];
        consts[6] = s;
    } else if (lane == 5) {
        consts[1] = consts[0] / (float)EE;
    }
}

// ---------------- fp32 tiled GEMM: C[M,TN] = A[M,K] @ B[K,TN], bf16 or f32 out ----------------
template <int TM, int TN, int TK, int RM, int RN, bool BF16OUT>
__global__ __launch_bounds__(256) void gemm_kernel(const float* __restrict__ A,
                                                   const float* __restrict__ B,
                                                   void* __restrict__ Cv, int M, int K) {
    static_assert(TM * TN == 256 * RM * RN, "thread coverage");
    static_assert(RN % 2 == 0, "pairable");
    __shared__ float As[TK][TM + 4];
    __shared__ float Bs[TK][TN];
    int tid = threadIdx.x;
    int tx = tid % (TN / RN);
    int ty = tid / (TN / RN);
    int blockRow = blockIdx.x * TM;
    float acc[RM][RN];
    #pragma unroll
    for (int i = 0; i < RM; i++)
        #pragma unroll
        for (int j = 0; j < RN; j++) acc[i][j] = 0.f;

    for (int k0 = 0; k0 < K; k0 += TK) {
        #pragma unroll
        for (int l = 0; l < TM * TK; l += 256 * 4) {
            int ll = l + tid * 4;
            if (ll < TM * TK) {
                int r = ll / TK, kk = ll % TK;
                float4 v = make_float4(0.f, 0.f, 0.f, 0.f);
                int gr = blockRow + r;
                if (gr < M) v = *(const float4*)(A + (size_t)gr * K + k0 + kk);
                As[kk + 0][r] = v.x;
                As[kk + 1][r] = v.y;
                As[kk + 2][r] = v.z;
                As[kk + 3][r] = v.w;
            }
        }
        #pragma unroll
        for (int l = 0; l < TK * TN; l += 256 * 4) {
            int ll = l + tid * 4;
            if (ll < TK * TN) {
                int kk = ll / TN, c = ll % TN;
                *(float4*)&Bs[kk][c] = *(const float4*)(B + (size_t)(k0 + kk) * TN + c);
            }
        }
        __syncthreads();
        #pragma unroll
        for (int k = 0; k < TK; k++) {
            float af[RM], bf[RN];
            #pragma unroll
            for (int i = 0; i < RM; i++) af[i] = As[k][ty * RM + i];
            #pragma unroll
            for (int j = 0; j < RN; j++) bf[j] = Bs[k][tx * RN + j];
            #pragma unroll
            for (int i = 0; i < RM; i++)
                #pragma unroll
                for (int j = 0; j < RN; j++) acc[i][j] += af[i] * bf[j];
        }
        __syncthreads();
    }
    #pragma unroll
    for (int i = 0; i < RM; i++) {
        int gr = blockRow + ty * RM + i;
        if (gr < M) {
            if (BF16OUT) {
                unsigned short* C = (unsigned short*)Cv;
                #pragma unroll
                for (int j = 0; j < RN; j += 2) {
                    unsigned int pk = (unsigned int)f2bf(acc[i][j]) |
                                      ((unsigned int)f2bf(acc[i][j + 1]) << 16);
                    *(unsigned int*)(C + (size_t)gr * TN + tx * RN + j) = pk;
                }
            } else {
                float* C = (float*)Cv;
                #pragma unroll
                for (int j = 0; j < RN; j++) C[(size_t)gr * TN + tx * RN + j] = acc[i][j];
            }
        }
    }
}

// ---------------- attention logits per node (bf16 inputs) ----------------
__global__ void al1_kernel(const unsigned short* __restrict__ xs1b, const float* __restrict__ as1,
                           const float* __restrict__ ad1, float* __restrict__ als,
                           float* __restrict__ ald) {
    int t = blockIdx.x * 256 + threadIdx.x;
    if (t >= NN * 4) return;
    int h = t & 3;
    const unsigned int* xp = (const unsigned int*)(xs1b + (size_t)t * 32);
    const float* ap = as1 + h * 32;
    const float* dp = ad1 + h * 32;
    float s = 0.f, d = 0.f;
    #pragma unroll
    for (int q = 0; q < 16; q++) {
        float2 v = bf2f2(xp[q]);
        s += v.x * ap[q * 2] + v.y * ap[q * 2 + 1];
        d += v.x * dp[q * 2] + v.y * dp[q * 2 + 1];
    }
    als[t] = s;
    ald[t] = d;
}

__global__ void al2_kernel(const unsigned short* __restrict__ xs2b, const float* __restrict__ as2,
                           const float* __restrict__ ad2, float* __restrict__ als,
                           float* __restrict__ ald) {
    int t = blockIdx.x * 256 + threadIdx.x;
    if (t >= NN) return;
    const unsigned int* xp = (const unsigned int*)(xs2b + (size_t)t * 32);
    float s = 0.f, d = 0.f;
    #pragma unroll
    for (int q = 0; q < 16; q++) {
        float2 v = bf2f2(xp[q]);
        s += v.x * as2[q * 2] + v.y * as2[q * 2 + 1];
        d += v.x * ad2[q * 2] + v.y * ad2[q * 2 + 1];
    }
    als[t] = s;
    ald[t] = d;
}

// ---------------- conv1 aggregation: one wave per dst node (H=4, F=128, bf16 gather) ----------------
__global__ __launch_bounds__(256) void gat1_agg(
    const unsigned short* __restrict__ xs1b, const float* __restrict__ als,
    const float* __restrict__ ald, const unsigned long long* __restrict__ edgedat,
    const int* __restrict__ indptr, const float* __restrict__ consts,
    const float* __restrict__ b1, const float* __restrict__ g1,
    const float* __restrict__ be1, float* __restrict__ h1out) {
    __shared__ float exbuf[4][CAP1 * 4];
    __shared__ int srcbuf[4][CAP1];
    int wv = threadIdx.x >> 6;
    int lane = threadIdx.x & 63;
    int n = blockIdx.x * 4 + wv;   // grid is exact: NN % 4 == 0
    int start = indptr[n];
    int deg = indptr[n + 1] - start;
    float ea_mean = consts[1];
    float ce[4] = {consts[2], consts[3], consts[4], consts[5]};
    float4 a4d = *(const float4*)(ald + (size_t)n * 4);
    float aldh[4] = {a4d.x, a4d.y, a4d.z, a4d.w};
    float4 a4s = *(const float4*)(als + (size_t)n * 4);
    float alsn[4] = {a4s.x, a4s.y, a4s.z, a4s.w};
    float asl[4], mx[4];
    #pragma unroll
    for (int h = 0; h < 4; h++) {
        float a = lrelu(alsn[h] + aldh[h] + ea_mean * ce[h]);
        asl[h] = a;
        mx[h] = a;
    }
    const unsigned long long* edp = edgedat + start;
    // phase 1: alpha + max
    for (int i = lane; i < deg; i += 64) {
        int s; float eav;
        unpack_edge(edp[i], s, eav);
        float4 v4 = *(const float4*)(als + (size_t)s * 4);
        float alv[4] = {v4.x, v4.y, v4.z, v4.w};
        bool st = (i < CAP1);
        if (st) srcbuf[wv][i] = s;
        #pragma unroll
        for (int h = 0; h < 4; h++) {
            float a = lrelu(alv[h] + aldh[h] + eav * ce[h]);
            if (st) exbuf[wv][i * 4 + h] = a;
            mx[h] = fmaxf(mx[h], a);
        }
    }
    #pragma unroll
    for (int h = 0; h < 4; h++)
        for (int off = 32; off > 0; off >>= 1) mx[h] = fmaxf(mx[h], __shfl_xor(mx[h], off));
    // phase 2: sum of exp (LDS-resident for deg<=CAP1, which is ~always)
    float sm[4] = {0.f, 0.f, 0.f, 0.f};
    for (int i = lane; i < deg; i += 64) {
        if (i < CAP1) {
            #pragma unroll
            for (int h = 0; h < 4; h++) {
                float exv = __expf(exbuf[wv][i * 4 + h] - mx[h]);
                exbuf[wv][i * 4 + h] = exv;
                sm[h] += exv;
            }
        } else {
            int s; float eav;
            unpack_edge(edp[i], s, eav);
            float4 v4 = *(const float4*)(als + (size_t)s * 4);
            float alv[4] = {v4.x, v4.y, v4.z, v4.w};
            #pragma unroll
            for (int h = 0; h < 4; h++) {
                float a = lrelu(alv[h] + aldh[h] + eav * ce[h]);
                sm[h] += __expf(a - mx[h]);
            }
        }
    }
    #pragma unroll
    for (int h = 0; h < 4; h++)
        for (int off = 32; off > 0; off >>= 1) sm[h] += __shfl_xor(sm[h], off);
    float inv[4];
    #pragma unroll
    for (int h = 0; h < 4; h++) inv[h] = 1.0f / (sm[h] + __expf(asl[h] - mx[h]) + 1e-16f);
    // phase 3: weighted gather (bf16); lane holds features c, c+1
    int c = lane * 2;
    int h = lane >> 4;
    float winv = inv[h];
    float wsl = __expf(asl[h] - mx[h]) * winv;
    float2 vself = bf2f2(*(const unsigned int*)(xs1b + (size_t)n * HC + c));
    float accx = vself.x * wsl, accy = vself.y * wsl;
    int m = deg < CAP1 ? deg : CAP1;
    int i = 0;
    for (; i + 4 <= m; i += 4) {
        float w0 = exbuf[wv][(i + 0) * 4 + h] * winv;
        float w1 = exbuf[wv][(i + 1) * 4 + h] * winv;
        float w2 = exbuf[wv][(i + 2) * 4 + h] * winv;
        float w3 = exbuf[wv][(i + 3) * 4 + h] * winv;
        int s0 = srcbuf[wv][i + 0], s1 = srcbuf[wv][i + 1];
        int s2 = srcbuf[wv][i + 2], s3 = srcbuf[wv][i + 3];
        float2 v0 = bf2f2(*(const unsigned int*)(xs1b + (size_t)s0 * HC + c));
        float2 v1 = bf2f2(*(const unsigned int*)(xs1b + (size_t)s1 * HC + c));
        float2 v2 = bf2f2(*(const unsigned int*)(xs1b + (size_t)s2 * HC + c));
        float2 v3 = bf2f2(*(const unsigned int*)(xs1b + (size_t)s3 * HC + c));
        accx += v0.x * w0; accy += v0.y * w0;
        accx += v1.x * w1; accy += v1.y * w1;
        accx += v2.x * w2; accy += v2.y * w2;
        accx += v3.x * w3; accy += v3.y * w3;
    }
    for (; i < m; i++) {
        float w0 = exbuf[wv][i * 4 + h] * winv;
        int s0 = srcbuf[wv][i];
        float2 v0 = bf2f2(*(const unsigned int*)(xs1b + (size_t)s0 * HC + c));
        accx += v0.x * w0; accy += v0.y * w0;
    }
    for (; i < deg; i++) {  // LDS-spill fallback (deg > CAP1): recompute
        int s; float eav;
        unpack_edge(edp[i], s, eav);
        float a = lrelu(als[(size_t)s * 4 + h] + aldh[h] + eav * ce[h]);
        float w0 = __expf(a - mx[h]) * winv;
        float2 v0 = bf2f2(*(const unsigned int*)(xs1b + (size_t)s * HC + c));
        accx += v0.x * w0; accy += v0.y * w0;
    }
    // epilogue: +bias, bn(eval), elu
    float o0 = accx + b1[c];
    float o1 = accy + b1[c + 1];
    o0 = o0 * (g1[c] * BN_RS) + be1[c];
    o1 = o1 * (g1[c + 1] * BN_RS) + be1[c + 1];
    o0 = elu(o0);
    o1 = elu(o1);
    *(float2*)(h1out + (size_t)n * HC + c) = make_float2(o0, o1);
}

// ---------------- conv2 aggregation + fused MLP heads ----------------
__global__ __launch_bounds__(256) void gat2_agg(
    const unsigned short* __restrict__ xs2b, const float* __restrict__ als,
    const float* __restrict__ ald, const unsigned long long* __restrict__ edgedat,
    const int* __restrict__ indptr, const float* __restrict__ consts,
    const float* __restrict__ b2, const float* __restrict__ g2, const float* __restrict__ be2,
    const float* __restrict__ Wc1, const float* __restrict__ bc1,
    const float* __restrict__ Wc2, const float* __restrict__ bc2,
    const float* __restrict__ Wr1, const float* __restrict__ br1,
    const float* __restrict__ Wr2, const float* __restrict__ br2,
    float* __restrict__ hout, float* __restrict__ cls, float* __restrict__ reg) {
    __shared__ float exbuf[4][CAP2];
    __shared__ int srcbuf[4][CAP2];
    __shared__ float hbuf[4][32];
    int wv = threadIdx.x >> 6;
    int lane = threadIdx.x & 63;
    int n = blockIdx.x * 4 + wv;   // grid exact
    int start = indptr[n];
    int deg = indptr[n + 1] - start;
    float ea_mean = consts[1];
    float ce = consts[6];
    float aldn = ald[n];
    float a0 = lrelu(als[n] + aldn + ea_mean * ce);
    float mx = a0;
    const unsigned long long* edp = edgedat + start;
    for (int i = lane; i < deg; i += 64) {
        int s; float eav;
        unpack_edge(edp[i], s, eav);
        float a = lrelu(als[s] + aldn + eav * ce);
        if (i < CAP2) { srcbuf[wv][i] = s; exbuf[wv][i] = a; }
        mx = fmaxf(mx, a);
    }
    for (int off = 32; off > 0; off >>= 1) mx = fmaxf(mx, __shfl_xor(mx, off));
    float sm = 0.f;
    for (int i = lane; i < deg; i += 64) {
        if (i < CAP2) {
            float exv = __expf(exbuf[wv][i] - mx);
            exbuf[wv][i] = exv;
            sm += exv;
        } else {
            int s; float eav;
            unpack_edge(edp[i], s, eav);
            float a = lrelu(als[s] + aldn + eav * ce);
            sm += __expf(a - mx);
        }
    }
    for (int off = 32; off > 0; off >>= 1) sm += __shfl_xor(sm, off);
    float invd = 1.0f / (sm + __expf(a0 - mx) + 1e-16f);
    // phase 3: 4 edges in parallel; 16 lanes/edge, 2 features per lane (bf16x2 = 4B)
    int quarter = lane >> 4;
    int cl = lane & 15;
    int c = cl * 2;
    float accx = 0.f, accy = 0.f;
    if (quarter == 0) {
        float2 vs = bf2f2(*(const unsigned int*)(xs2b + (size_t)n * CD + c));
        float wsl = __expf(a0 - mx) * invd;
        accx = vs.x * wsl; accy = vs.y * wsl;
    }
    int m = deg < CAP2 ? deg : CAP2;
    for (int i = quarter; i < m; i += 4) {
        float w0 = exbuf[wv][i] * invd;
        int s0 = srcbuf[wv][i];
        float2 v0 = bf2f2(*(const unsigned int*)(xs2b + (size_t)s0 * CD + c));
        accx += v0.x * w0; accy += v0.y * w0;
    }
    for (int i = CAP2 + quarter; i < deg; i += 4) {  // spill fallback
        int s; float eav;
        unpack_edge(edp[i], s, eav);
        float a = lrelu(als[s] + aldn + eav * ce);
        float w0 = __expf(a - mx) * invd;
        float2 v0 = bf2f2(*(const unsigned int*)(xs2b + (size_t)s * CD + c));
        accx += v0.x * w0; accy += v0.y * w0;
    }
    accx += __shfl_xor(accx, 16); accy += __shfl_xor(accy, 16);
    accx += __shfl_xor(accx, 32); accy += __shfl_xor(accy, 32);
    if (lane < 16) {
        float o0 = accx + b2[c];
        float o1 = accy + b2[c + 1];
        o0 = o0 * (g2[c] * BN_RS) + be2[c];
        o1 = o1 * (g2[c + 1] * BN_RS) + be2[c + 1];
        o0 = elu(o0);
        o1 = elu(o1);
        hbuf[wv][c] = o0;
        hbuf[wv][c + 1] = o1;
        *(float2*)(hout + (size_t)n * CD + c) = make_float2(o0, o1);
    }
    __syncthreads();
    // fused heads: lanes 0-15 classifier hidden unit j, lanes 16-31 regressor hidden unit j
    float r0 = 0.f, r1 = 0.f;
    if (lane < 32) {
        int j = lane & 15;
        bool iscls = lane < 16;
        float s = iscls ? bc1[j] : br1[j];
        #pragma unroll
        for (int cc = 0; cc < 32; cc++) {
            float w = iscls ? Wc1[cc * 16 + j] : Wr1[cc * 16 + j];
            s += hbuf[wv][cc] * w;
        }
        s = fmaxf(s, 0.f);
        if (iscls) { r0 = s * Wc2[j * 2]; r1 = s * Wc2[j * 2 + 1]; }
        else       { r0 = s * Wr2[j]; }
    }
    #pragma unroll
    for (int off = 1; off < 16; off <<= 1) {
        r0 += __shfl_xor(r0, off);
        r1 += __shfl_xor(r1, off);
    }
    if (lane == 0)  *(float2*)(cls + (size_t)n * 2) = make_float2(r0 + bc2[0], r1 + bc2[1]);
    if (lane == 16) reg[n] = r0 + br2[0];
}

// ---------------- launch ----------------
extern "C" void kernel_launch(void* const* d_in, const int* in_sizes, int n_in,
                              void* d_out, int out_size, void* d_ws, size_t ws_size,
                              hipStream_t stream) {
    const float* x   = (const float*)d_in[0];
    const int*   ei  = (const int*)d_in[1];
    const float* ea  = (const float*)d_in[2];
    const float* W1  = (const float*)d_in[3];
    const float* as1 = (const float*)d_in[4];
    const float* ad1 = (const float*)d_in[5];
    const float* We1 = (const float*)d_in[6];
    const float* ae1 = (const float*)d_in[7];
    const float* b1  = (const float*)d_in[8];
    const float* g1  = (const float*)d_in[9];
    const float* be1 = (const float*)d_in[10];
    const float* W2  = (const float*)d_in[11];
    const float* as2 = (const float*)d_in[12];
    const float* ad2 = (const float*)d_in[13];
    const float* We2 = (const float*)d_in[14];
    const float* ae2 = (const float*)d_in[15];
    const float* b2  = (const float*)d_in[16];
    const float* g2  = (const float*)d_in[17];
    const float* be2 = (const float*)d_in[18];
    const float* Wc1 = (const float*)d_in[19];
    const float* bc1 = (const float*)d_in[20];
    const float* Wc2 = (const float*)d_in[21];
    const float* bc2 = (const float*)d_in[22];
    const float* Wr1 = (const float*)d_in[23];
    const float* br1 = (const float*)d_in[24];
    const float* Wr2 = (const float*)d_in[25];
    const float* br2 = (const float*)d_in[26];

    char* ws = (char*)d_ws;
    unsigned short* xs1b = (unsigned short*)(ws + 0);          // N*128 bf16 = 12.8 MB
    float* h1            = (float*)(ws + 12800000);            // N*128 f32 = 25.6 MB
    unsigned short* xs2b = (unsigned short*)(ws + 38400000);   // N*32 bf16 = 3.2 MB
    float* als1          = (float*)(ws + 41600000);            // N*4
    float* ald1          = (float*)(ws + 42400000);            // N*4
    float* als2          = (float*)(ws + 43200000);            // N
    float* ald2          = (float*)(ws + 43400000);            // N
    float* consts        = (float*)(ws + 43600000);            // 8 floats
    int*   counts        = (int*)(ws + 43600128);              // N
    int*   indptr        = (int*)(ws + 43800128);              // N+1 (padded)
    int*   partials      = (int*)(ws + 44000136);              // 64
    int*   localbuf      = (int*)(ws + 44000400);              // N
    int*   rank          = (int*)(ws + 44200400);              // E = 6.4 MB
    unsigned long long* edgedat = (unsigned long long*)(ws + 50600400);  // E*8 = 12.8 MB (ends ~63.4 MB)

    float* out_cls = (float*)d_out;            // [N,2]
    float* out_reg = out_cls + 2 * NN;         // [N]
    float* out_h   = out_cls + 3 * NN;         // [N,32]

    hipMemsetAsync(counts, 0, NN * sizeof(int), stream);
    hipMemsetAsync(consts, 0, 8 * sizeof(float), stream);

    // CSR build + edge mean (rank captured in count; scatter is atomic-free)
    count_kernel<<<(EE + 2047) / 2048, 256, 0, stream>>>(ei, ea, counts, rank, consts);
    scan_local<<<(NN + 1023) / 1024, 256, 0, stream>>>(counts, localbuf, partials, NN);
    scan_part<<<1, 64, 0, stream>>>(partials, indptr, (NN + 1023) / 1024);
    scan_add<<<(NN + 1023) / 1024, 256, 0, stream>>>(localbuf, partials, indptr, NN);
    scatter_kernel<<<(EE + 2047) / 2048, 256, 0, stream>>>(ei, ea, rank, indptr, edgedat);
    prep_kernel<<<1, 64, 0, stream>>>(We1, ae1, We2, ae2, consts);

    // conv1
    gemm_kernel<64, 128, 32, 4, 8, true><<<(NN + 63) / 64, 256, 0, stream>>>(x, W1, xs1b, NN, IN_DIM);
    al1_kernel<<<(NN * 4 + 255) / 256, 256, 0, stream>>>(xs1b, as1, ad1, als1, ald1);
    gat1_agg<<<NN / 4, 256, 0, stream>>>(xs1b, als1, ald1, edgedat, indptr, consts,
                                         b1, g1, be1, h1);
    // conv2
    gemm_kernel<128, 32, 32, 8, 2, true><<<(NN + 127) / 128, 256, 0, stream>>>(h1, W2, xs2b, NN, HC);
    al2_kernel<<<(NN + 255) / 256, 256, 0, stream>>>(xs2b, as2, ad2, als2, ald2);
    gat2_agg<<<NN / 4, 256, 0, stream>>>(xs2b, als2, ald2, edgedat, indptr, consts,
                                         b2, g2, be2, Wc1, bc1, Wc2, bc2,
                                         Wr1, br1, Wr2, br2, out_h, out_cls, out_reg);
}